// Round 8
// baseline (2133.336 us; speedup 1.0000x reference)
//
#include <hip/hip_runtime.h>

// EntityAttentionRNNMsgAgent — fused MI355X implementation.
// Stages:
//  K0:  transpose all weights to f16 [N][K] (gate branch: hi/lo split pair)
//  K0w: gate-tail collapse: Weff = Wout@Wg2, Wveff (256x8), beff — f32, 1 block
//  K1gA: gate branch GEMMs (x1, Q, K-all, v2) -> f32 temps in ws.
//        r8: A-fragments register-resident per wave (ds_reads 176->32/wave).
//  K1gB: gate logits as plain f32 dot products + softmax + P.v2 in registers
//  K1<0> x2 main, K1<0> x2_msg
//  K2:  gated_msg, global attention, fc2, gru-input GEMM (gi); reads gate flag
//  K3:  64-step GRU, row-partitioned (32 blocks x 16 rows), h resident in LDS.
//       r8: back to 256 threads (r7's 1024-thr was a regression) + full-step
//       gi software pipeline (g[t+1] prefetched during step t).
//  K4:  q = hs @ fc3 + b, masked

#define DEV __device__ __forceinline__

typedef _Float16 f16x8 __attribute__((ext_vector_type(8)));
typedef _Float16 f16x4 __attribute__((ext_vector_type(4)));
typedef float    f32x4 __attribute__((ext_vector_type(4)));

DEV f32x4 mfma16(f16x8 a, f16x8 b, f32x4 c){
  return __builtin_amdgcn_mfma_f32_16x16x32_f16(a, b, c, 0, 0, 0);
}

// A/B fragment pair for optional split-precision (MODE=1: value = hi + lo)
template<int MODE> struct AB {
  f16x8 hi, lo;
  DEV void mf(const AB& b, f32x4& c) const {
    if constexpr (MODE){
      c = mfma16(lo, b.hi, c);
      c = mfma16(hi, b.lo, c);
    }
    c = mfma16(hi, b.hi, c);
  }
};

template<int MODE> DEV AB<MODE> ldW(const _Float16* p, int losz){
  AB<MODE> r; r.hi = *(const f16x8*)p;
  if constexpr (MODE) r.lo = *(const f16x8*)(p + losz);
  return r;
}
template<int MODE> DEV AB<MODE> ldL(const _Float16* ph, const _Float16* pl){
  AB<MODE> r; r.hi = *(const f16x8*)ph;
  if constexpr (MODE) r.lo = *(const f16x8*)pl;
  return r;
}
template<int MODE> DEV AB<MODE> ldF(const float* p){
  AB<MODE> r;
  f32x4 v0 = *(const f32x4*)p, v1 = *(const f32x4*)(p + 4);
#pragma unroll
  for (int i = 0; i < 4; ++i){
    float a = v0[i], b = v1[i];
    _Float16 ah = (_Float16)a, bh = (_Float16)b;
    r.hi[i] = ah; r.hi[i+4] = bh;
    if constexpr (MODE){
      r.lo[i]   = (_Float16)(a - (float)ah);
      r.lo[i+4] = (_Float16)(b - (float)bh);
    }
  }
  return r;
}
template<int MODE> DEV void stL(_Float16* ph, _Float16* pl, int idx, float v){
  _Float16 h = (_Float16)v;
  ph[idx] = h;
  if constexpr (MODE) pl[idx] = (_Float16)(v - (float)h);
}

// ---------------------------------------------------------------- K0: weights
struct WJobs {
  const float* src[15];
  unsigned off[15];
  int K[15], N[15], mode[15];
};

__global__ __launch_bounds__(256) void k0_conv(WJobs jb, char* ws){
  const int job = blockIdx.y;
  const int K = jb.K[job], N = jb.N[job];
  const int total = K * N;
  _Float16* dh = (_Float16*)(ws + jb.off[job]);
  const float* src = jb.src[job];
  const int m = jb.mode[job];
  for (int idx = blockIdx.x*256 + threadIdx.x; idx < total; idx += gridDim.x*256){
    int n = idx / K, k = idx - n*K;
    float v = src[(size_t)k*N + n];
    _Float16 h = (_Float16)v;
    dh[idx] = h;
    if (m) dh[total + idx] = (_Float16)(v - (float)h);
  }
}

// ------------------------------------------------- K0w: gate-tail precompute
__global__ __launch_bounds__(256) void k0w_gate(
    const float* __restrict__ Wout, const float* __restrict__ Wg2,
    const float* __restrict__ bo,   const float* __restrict__ Win,
    _Float16* __restrict__ wveff, float* __restrict__ beff)
{
  __shared__ float weff_s[256*2];
  const int tid = threadIdx.x;
  {
    float a0 = 0.f, a1 = 0.f;
    const float* wr = Wout + (size_t)tid*256;
    for (int f = 0; f < 256; ++f){ float x = wr[f]; a0 += x*Wg2[2*f]; a1 += x*Wg2[2*f+1]; }
    weff_s[tid*2] = a0; weff_s[tid*2+1] = a1;
  }
  if (tid < 2){
    float s = 0.f;
    for (int f = 0; f < 256; ++f) s += bo[f]*Wg2[2*f + tid];
    beff[tid] = s;
  }
  __syncthreads();
  {
    const int j = tid;
    for (int n = 0; n < 16; ++n){
      float v = 0.f;
      if (n < 8){
        int h = n >> 1, c = n & 1;
        const float* wr = Win + (size_t)j*768 + 512 + h*64;
        const float* we = weff_s + (h*64)*2 + c;
        for (int d = 0; d < 64; ++d) v += wr[d]*we[2*d];
      }
      _Float16 hi = (_Float16)v;
      wveff[n*256 + j] = hi;
      wveff[16*256 + n*256 + j] = (_Float16)(v - (float)hi);
    }
  }
}

// --------------------------------------------- K1gA: gate GEMMs -> f32 ws
// 512 threads, one block per batch item. LDS = x1 pair only. 2 barriers.
// Phase 2: A-fragments held in registers, reused across all B-tiles of a wave.
__global__ __launch_bounds__(512) void k1ga(
    const float* __restrict__ ent,
    const _Float16* __restrict__ W1, const float* __restrict__ b1,
    const _Float16* __restrict__ WIN,
    const _Float16* __restrict__ WVEFF,
    float* __restrict__ Kg, float* __restrict__ Qg, float* __restrict__ v2g)
{
  constexpr int W1SZ = 96*256, WINSZ = 256*768, WVSZ = 16*256;
  const int b = blockIdx.x;
  const int tid = threadIdx.x;
  const int w = tid >> 6, lg = (tid >> 4) & 3, li = tid & 15;

  extern __shared__ char smem[];
  _Float16* x1h = (_Float16*)smem;                 // 64*264 f16
  _Float16* x1l = (_Float16*)(smem + 64*264*2);    // 64*264 f16

  // ---- phase 1: x1 = relu(ent @ W1 + b1)
  {
    const int mt = w >> 1;
    f32x4 acc[8];
#pragma unroll
    for (int c = 0; c < 8; ++c) acc[c] = 0.f;
#pragma unroll
    for (int kk = 0; kk < 3; ++kk){
      AB<1> a = ldF<1>(ent + ((size_t)b*64 + mt*16 + li)*96 + kk*32 + lg*8);
#pragma unroll
      for (int c = 0; c < 8; ++c){
        int nt = (w & 1)*8 + c;
        AB<1> bb = ldW<1>(W1 + (size_t)(nt*16 + li)*96 + kk*32 + lg*8, W1SZ);
        a.mf(bb, acc[c]);
      }
    }
#pragma unroll
    for (int c = 0; c < 8; ++c){
      int col = ((w & 1)*8 + c)*16 + li;
      float bias = b1[col];
#pragma unroll
      for (int j = 0; j < 4; ++j){
        float v = fmaxf(acc[c][j] + bias, 0.f);
        stL<1>(x1h, x1l, (mt*16 + 4*lg + j)*264 + col, v);
      }
    }
  }
  __syncthreads();

  // ---- phase 2a: K (+v2). wave w -> rowgroup rg=w>>1, B-half bh=w&1.
  {
    const int rg = w >> 1, bh = w & 1;
    f16x8 Ah[8], Al[8];
#pragma unroll
    for (int kk = 0; kk < 8; ++kk){
      int ao = (rg*16 + li)*264 + kk*32 + lg*8;
      Ah[kk] = *(const f16x8*)(x1h + ao);
      Al[kk] = *(const f16x8*)(x1l + ao);
    }
#pragma unroll
    for (int c = 0; c < 8; ++c){
      int nt = bh*8 + c;
      const _Float16* bp = WIN + (size_t)(256 + nt*16 + li)*256 + lg*8;
      f32x4 acc = 0.f;
#pragma unroll
      for (int kk = 0; kk < 8; ++kk){
        f16x8 Bh = *(const f16x8*)(bp + kk*32);
        f16x8 Bl = *(const f16x8*)(bp + WINSZ + kk*32);
        acc = mfma16(Al[kk], Bh, acc);
        acc = mfma16(Ah[kk], Bl, acc);
        acc = mfma16(Ah[kk], Bh, acc);
      }
#pragma unroll
      for (int r = 0; r < 4; ++r)
        Kg[(size_t)b*16384 + (size_t)((rg*16 + 4*lg + r)*256 + nt*16 + li)] = acc[r];
    }
    if (bh == 0){   // v2 for rowgroup rg (same A-frags)
      const _Float16* bp = WVEFF + (size_t)li*256 + lg*8;
      f32x4 acc = 0.f;
#pragma unroll
      for (int kk = 0; kk < 8; ++kk){
        f16x8 Bh = *(const f16x8*)(bp + kk*32);
        f16x8 Bl = *(const f16x8*)(bp + WVSZ + kk*32);
        acc = mfma16(Al[kk], Bh, acc);
        acc = mfma16(Ah[kk], Bl, acc);
        acc = mfma16(Ah[kk], Bh, acc);
      }
#pragma unroll
      for (int r = 0; r < 4; ++r)
        v2g[(size_t)b*1024 + (size_t)((rg*16 + 4*lg + r)*16 + li)] = acc[r];
    }
  }
  // ---- phase 2b: Q. A rows 0..15 for all waves; wave w -> col-tiles 2w,2w+1.
  {
    f16x8 Ah[8], Al[8];
#pragma unroll
    for (int kk = 0; kk < 8; ++kk){
      int ao = li*264 + kk*32 + lg*8;
      Ah[kk] = *(const f16x8*)(x1h + ao);
      Al[kk] = *(const f16x8*)(x1l + ao);
    }
#pragma unroll
    for (int s = 0; s < 2; ++s){
      int nt = w*2 + s;
      const _Float16* bp = WIN + (size_t)(nt*16 + li)*256 + lg*8;
      f32x4 acc = 0.f;
#pragma unroll
      for (int kk = 0; kk < 8; ++kk){
        f16x8 Bh = *(const f16x8*)(bp + kk*32);
        f16x8 Bl = *(const f16x8*)(bp + WINSZ + kk*32);
        acc = mfma16(Al[kk], Bh, acc);
        acc = mfma16(Ah[kk], Bl, acc);
        acc = mfma16(Ah[kk], Bh, acc);
      }
#pragma unroll
      for (int r = 0; r < 4; ++r)
        Qg[(size_t)b*4096 + (size_t)((4*lg + r)*256 + nt*16 + li)] = acc[r];
    }
  }
}

// --------------------------------------------- K1gB: logits/softmax/og, f32
__global__ __launch_bounds__(256) void k1gb(
    const float* __restrict__ om, const float* __restrict__ em,
    const float* __restrict__ Kg, const float* __restrict__ Qg,
    const float* __restrict__ v2g,
    const float* __restrict__ beff, const float* __restrict__ gb2,
    float* __restrict__ og, float* __restrict__ gate)
{
  const int b = blockIdx.x;
  const int tid = threadIdx.x;

  __shared__ float Qs[16*260];
  __shared__ float v2s[64*18];

  for (int idx = tid; idx < 4096; idx += 256){
    int r = idx >> 8, d = idx & 255;
    Qs[r*260 + d] = Qg[(size_t)b*4096 + idx];
  }
  for (int idx = tid; idx < 1024; idx += 256)
    v2s[(idx >> 4)*18 + (idx & 15)] = v2g[(size_t)b*1024 + idx];
  __syncthreads();

  const int q = tid >> 4, i16 = tid & 15;
  float acc0 = 0.f, acc1 = 0.f;
  for (int h = 0; h < 4; ++h){
    float lg_[4];
#pragma unroll
    for (int u = 0; u < 4; ++u){
      int key = i16 + 16*u;
      const float* kp = Kg + (size_t)b*16384 + (size_t)key*256 + h*64;
      const float* qp = Qs + q*260 + h*64;
      float s = 0.f;
      for (int d = 0; d < 64; ++d) s += qp[d]*kp[d];
      float m = om[((size_t)b*64 + q)*64 + key];
      lg_[u] = (m > 0.f) ? -1e9f : s*0.125f;
    }
    float mx = fmaxf(fmaxf(lg_[0], lg_[1]), fmaxf(lg_[2], lg_[3]));
#pragma unroll
    for (int d = 1; d < 16; d <<= 1) mx = fmaxf(mx, __shfl_xor(mx, d, 16));
    float pv[4], ssum = 0.f;
#pragma unroll
    for (int u = 0; u < 4; ++u){ pv[u] = expf(lg_[u] - mx); ssum += pv[u]; }
#pragma unroll
    for (int d = 1; d < 16; d <<= 1) ssum += __shfl_xor(ssum, d, 16);
#pragma unroll
    for (int u = 0; u < 4; ++u){
      int key = i16 + 16*u;
      float m = om[((size_t)b*64 + q)*64 + key];
      float p = (pv[u]/ssum)*(1.f - m);
      acc0 += p * v2s[key*18 + h*2];
      acc1 += p * v2s[key*18 + h*2 + 1];
    }
  }
#pragma unroll
  for (int d = 1; d < 16; d <<= 1){
    acc0 += __shfl_xor(acc0, d, 16);
    acc1 += __shfl_xor(acc1, d, 16);
  }
  if (i16 == 0){
    float am = em[(size_t)b*64 + q];
    float g0 = (1.f - am)*(acc0 + beff[0]) + gb2[0];
    float g1 = (1.f - am)*(acc1 + beff[1]) + gb2[1];
    og[((size_t)b*16 + q)*2]     = g0;
    og[((size_t)b*16 + q)*2 + 1] = g1;
    gate[(size_t)b*16 + q] = (g1 > g0) ? 1.f : 0.f;
  }
}

// ------------------------------------------------------- K1: branch attention
// One block per batch item. 256 threads = 4 waves. outp staged f16.
template<int MODE>
__global__ __launch_bounds__(256) void k1_branch(
    const float* __restrict__ ent, const float* __restrict__ om, const float* __restrict__ em,
    const _Float16* __restrict__ W1, const float* __restrict__ b1,
    const _Float16* __restrict__ WIN,
    const _Float16* __restrict__ WOUT, const float* __restrict__ bo,
    float* __restrict__ x2out)
{
  constexpr int W1SZ = 96*256, WINSZ = 256*768, WOUTSZ = 256*256;
  const int b = blockIdx.x;
  const int tid = threadIdx.x;
  const int w = tid >> 6, lg = (tid >> 4) & 3, li = tid & 15;

  extern __shared__ char smem[];
  char* sp = smem;
  _Float16* x1h = (_Float16*)sp; sp += 64*264*2;
  _Float16* x1l = x1h; if constexpr (MODE){ x1l = (_Float16*)sp; sp += 64*264*2; }
  _Float16* Kh  = (_Float16*)sp; sp += 64*72*2;
  _Float16* Kl  = Kh;  if constexpr (MODE){ Kl = (_Float16*)sp; sp += 64*72*2; }
  _Float16* Vh  = (_Float16*)sp; sp += 64*72*2;   // V transposed: [dim][key]
  _Float16* Vl  = Vh;  if constexpr (MODE){ Vl = (_Float16*)sp; sp += 64*72*2; }
  _Float16* Qh  = (_Float16*)sp; sp += 16*72*2;
  _Float16* Ql  = Qh;  if constexpr (MODE){ Ql = (_Float16*)sp; sp += 16*72*2; }
  float*    lgs = (float*)sp;    sp += 16*72*4;
  _Float16* Ph  = (_Float16*)sp; sp += 16*72*2;
  _Float16* Pl  = Ph;  if constexpr (MODE){ Pl = (_Float16*)sp; sp += 16*72*2; }
  _Float16* outp = (_Float16*)sp; sp += 16*264*2;

  // ---- phase 1: x1 = relu(ent @ W1 + b1)   (M=64,K=96,N=256)
  {
    f32x4 acc[4][4];
#pragma unroll
    for (int r = 0; r < 4; ++r)
#pragma unroll
      for (int c = 0; c < 4; ++c) acc[r][c] = 0.f;
#pragma unroll
    for (int kk = 0; kk < 3; ++kk){
      AB<MODE> a[4];
#pragma unroll
      for (int r = 0; r < 4; ++r)
        a[r] = ldF<MODE>(ent + ((size_t)b*64 + 16*r + li)*96 + kk*32 + lg*8);
#pragma unroll
      for (int c = 0; c < 4; ++c){
        AB<MODE> bb = ldW<MODE>(W1 + (size_t)(64*w + 16*c + li)*96 + kk*32 + lg*8, W1SZ);
#pragma unroll
        for (int r = 0; r < 4; ++r) a[r].mf(bb, acc[r][c]);
      }
    }
#pragma unroll
    for (int c = 0; c < 4; ++c){
      int col = 64*w + 16*c + li;
      float bias = b1[col];
#pragma unroll
      for (int r = 0; r < 4; ++r)
#pragma unroll
        for (int j = 0; j < 4; ++j){
          float v = fmaxf(acc[r][c][j] + bias, 0.f);
          stL<MODE>(x1h, x1l, (16*r + 4*lg + j)*264 + col, v);
        }
    }
  }
  __syncthreads();

  // ---- phase 2: per-head attention
  for (int h = 0; h < 4; ++h){
    { // K_h
      f32x4 acc[4];
#pragma unroll
      for (int c = 0; c < 4; ++c) acc[c] = 0.f;
      for (int kk = 0; kk < 8; ++kk){
        int ao = (16*w + li)*264 + kk*32 + lg*8;
        AB<MODE> a = ldL<MODE>(x1h + ao, x1l + ao);
#pragma unroll
        for (int c = 0; c < 4; ++c){
          AB<MODE> bb = ldW<MODE>(WIN + (size_t)(256 + 64*h + 16*c + li)*256 + kk*32 + lg*8, WINSZ);
          a.mf(bb, acc[c]);
        }
      }
#pragma unroll
      for (int c = 0; c < 4; ++c)
#pragma unroll
        for (int j = 0; j < 4; ++j)
          stL<MODE>(Kh, Kl, (16*w + 4*lg + j)*72 + 16*c + li, acc[c][j]);
    }
    { // V_h (stored transposed)
      f32x4 acc[4];
#pragma unroll
      for (int c = 0; c < 4; ++c) acc[c] = 0.f;
      for (int kk = 0; kk < 8; ++kk){
        int ao = (16*w + li)*264 + kk*32 + lg*8;
        AB<MODE> a = ldL<MODE>(x1h + ao, x1l + ao);
#pragma unroll
        for (int c = 0; c < 4; ++c){
          AB<MODE> bb = ldW<MODE>(WIN + (size_t)(512 + 64*h + 16*c + li)*256 + kk*32 + lg*8, WINSZ);
          a.mf(bb, acc[c]);
        }
      }
#pragma unroll
      for (int c = 0; c < 4; ++c)
#pragma unroll
        for (int j = 0; j < 4; ++j)
          stL<MODE>(Vh, Vl, (16*c + li)*72 + 16*w + 4*lg + j, acc[c][j]);
    }
    { // Q_h
      f32x4 acc = 0.f;
      for (int kk = 0; kk < 8; ++kk){
        int ao = li*264 + kk*32 + lg*8;
        AB<MODE> a = ldL<MODE>(x1h + ao, x1l + ao);
        AB<MODE> bb = ldW<MODE>(WIN + (size_t)(64*h + 16*w + li)*256 + kk*32 + lg*8, WINSZ);
        a.mf(bb, acc);
      }
#pragma unroll
      for (int j = 0; j < 4; ++j)
        stL<MODE>(Qh, Ql, (4*lg + j)*72 + 16*w + li, acc[j]);
    }
    __syncthreads();
    { // logits
      f32x4 acc = 0.f;
#pragma unroll
      for (int kk = 0; kk < 2; ++kk){
        int ao = li*72 + kk*32 + lg*8;
        AB<MODE> a = ldL<MODE>(Qh + ao, Ql + ao);
        int bo_ = (16*w + li)*72 + kk*32 + lg*8;
        AB<MODE> bb = ldL<MODE>(Kh + bo_, Kl + bo_);
        a.mf(bb, acc);
      }
#pragma unroll
      for (int j = 0; j < 4; ++j){
        int q = 4*lg + j, key = 16*w + li;
        float v = acc[j] * 0.125f;
        float m = om[((size_t)b*64 + q)*64 + key];
        if (m > 0.f) v = -1e9f;
        lgs[q*72 + key] = v;
      }
    }
    __syncthreads();
    { // softmax
      int q = tid >> 4, i16 = tid & 15;
      float pv[4], mx = -3e38f;
#pragma unroll
      for (int u = 0; u < 4; ++u){ pv[u] = lgs[q*72 + i16 + 16*u]; mx = fmaxf(mx, pv[u]); }
#pragma unroll
      for (int d = 1; d < 16; d <<= 1) mx = fmaxf(mx, __shfl_xor(mx, d, 16));
      float s = 0.f;
#pragma unroll
      for (int u = 0; u < 4; ++u){ pv[u] = expf(pv[u] - mx); s += pv[u]; }
#pragma unroll
      for (int d = 1; d < 16; d <<= 1) s += __shfl_xor(s, d, 16);
#pragma unroll
      for (int u = 0; u < 4; ++u){
        int key = i16 + 16*u;
        float m = om[((size_t)b*64 + q)*64 + key];
        stL<MODE>(Ph, Pl, q*72 + key, (pv[u]/s)*(1.f - m));
      }
    }
    __syncthreads();
    { // out_h = P @ V_h
      f32x4 acc = 0.f;
#pragma unroll
      for (int kk = 0; kk < 2; ++kk){
        int ao = li*72 + kk*32 + lg*8;
        AB<MODE> a = ldL<MODE>(Ph + ao, Pl + ao);
        int bo_ = (16*w + li)*72 + kk*32 + lg*8;
        AB<MODE> bb = ldL<MODE>(Vh + bo_, Vl + bo_);
        a.mf(bb, acc);
      }
#pragma unroll
      for (int j = 0; j < 4; ++j)
        outp[(4*lg + j)*264 + 64*h + 16*w + li] = (_Float16)acc[j];
    }
    __syncthreads();
  }

  // ---- phase 3: out-proj + bias + post-mask
  {
    f32x4 acc[4];
#pragma unroll
    for (int c = 0; c < 4; ++c) acc[c] = 0.f;
    for (int kk = 0; kk < 8; ++kk){
      AB<MODE> a{};
      a.hi = *(const f16x8*)(outp + li*264 + kk*32 + lg*8);
#pragma unroll
      for (int c = 0; c < 4; ++c){
        AB<MODE> bb = ldW<MODE>(WOUT + (size_t)(64*w + 16*c + li)*256 + kk*32 + lg*8, WOUTSZ);
        a.mf(bb, acc[c]);
      }
    }
#pragma unroll
    for (int c = 0; c < 4; ++c){
      int col = 64*w + 16*c + li;
      float bias = bo[col];
#pragma unroll
      for (int j = 0; j < 4; ++j){
        int q = 4*lg + j;
        float v = (acc[c][j] + bias) * (1.f - em[(size_t)b*64 + q]);
        x2out[((size_t)b*16 + q)*256 + col] = v;
      }
    }
  }
}

// ----------------------------------------- K2: gate, global attention, fc2, gi
__global__ __launch_bounds__(256) void k2_global(
    const float* __restrict__ em,
    const float* __restrict__ x2, const float* __restrict__ x2m,
    const float* __restrict__ gate,
    const _Float16* __restrict__ GMIN, const _Float16* __restrict__ GMOUT, const float* __restrict__ gob,
    const _Float16* __restrict__ FC2T, const float* __restrict__ fc2b,
    const _Float16* __restrict__ GIHT, const float* __restrict__ gib,
    float* __restrict__ gi)
{
  const int b = blockIdx.x;
  const int tid = threadIdx.x;
  const int w = tid >> 6, lg = (tid >> 4) & 3, li = tid & 15;

  __shared__ float gate_s[16];
  __shared__ __align__(16) _Float16 gm_s[16*264];
  __shared__ __align__(16) _Float16 Q2[16*72];
  __shared__ __align__(16) _Float16 K2s[16*72];
  __shared__ __align__(16) _Float16 Vt2[64*40];
  __shared__ float lg2[16*24];
  __shared__ __align__(16) _Float16 P2[16*40];
  __shared__ __align__(16) float outp[16*264];
  __shared__ __align__(16) _Float16 cat_s[16*520];
  __shared__ __align__(16) _Float16 x3_s[16*264];

  if (tid < 16) gate_s[tid] = gate[(size_t)b*16 + tid];
  __syncthreads();
  for (int idx = tid; idx < 4096; idx += 256){
    int q = idx >> 8, d = idx & 255;
    gm_s[q*264 + d]  = (_Float16)(x2m[((size_t)b*16 + q)*256 + d] * gate_s[q]);
    cat_s[q*520 + d] = (_Float16)(x2[((size_t)b*16 + q)*256 + d]);
  }
  for (int idx = tid; idx < 64*40; idx += 256) Vt2[idx] = (_Float16)0.f;
  for (int idx = tid; idx < 16*40; idx += 256) P2[idx] = (_Float16)0.f;
  __syncthreads();
  for (int h = 0; h < 4; ++h){
    {
      f32x4 aq = 0.f, ak = 0.f, av = 0.f;
      for (int kk = 0; kk < 8; ++kk){
        f16x8 A  = *(const f16x8*)(gm_s + li*264 + kk*32 + lg*8);
        f16x8 Bq = *(const f16x8*)(GMIN + (size_t)(      64*h + 16*w + li)*256 + kk*32 + lg*8);
        f16x8 Bk = *(const f16x8*)(GMIN + (size_t)(256 + 64*h + 16*w + li)*256 + kk*32 + lg*8);
        f16x8 Bv = *(const f16x8*)(GMIN + (size_t)(512 + 64*h + 16*w + li)*256 + kk*32 + lg*8);
        aq = mfma16(A, Bq, aq); ak = mfma16(A, Bk, ak); av = mfma16(A, Bv, av);
      }
#pragma unroll
      for (int j = 0; j < 4; ++j){
        int rw = 4*lg + j, dim = 16*w + li;
        Q2[rw*72 + dim]  = (_Float16)aq[j];
        K2s[rw*72 + dim] = (_Float16)ak[j];
        Vt2[dim*40 + rw] = (_Float16)av[j];
      }
    }
    __syncthreads();
    if (w == 0){
      f32x4 acc = 0.f;
#pragma unroll
      for (int kk = 0; kk < 2; ++kk){
        f16x8 A = *(const f16x8*)(Q2  + li*72 + kk*32 + lg*8);
        f16x8 B = *(const f16x8*)(K2s + li*72 + kk*32 + lg*8);
        acc = mfma16(A, B, acc);
      }
      float amk = em[(size_t)b*64 + li];
#pragma unroll
      for (int j = 0; j < 4; ++j){
        int q = 4*lg + j;
        float amq = em[(size_t)b*64 + q];
        float m = 1.f - (1.f - amq)*(1.f - amk);
        float v = acc[j]*0.125f;
        if (m > 0.f) v = -1e9f;
        lg2[q*24 + li] = v;
      }
    }
    __syncthreads();
    {
      int q = tid >> 4, key = tid & 15;
      float v = lg2[q*24 + key];
      float mx = v;
#pragma unroll
      for (int d = 1; d < 16; d <<= 1) mx = fmaxf(mx, __shfl_xor(mx, d, 16));
      float pe = expf(v - mx);
      float s = pe;
#pragma unroll
      for (int d = 1; d < 16; d <<= 1) s += __shfl_xor(s, d, 16);
      float amq = em[(size_t)b*64 + q], amk = em[(size_t)b*64 + key];
      float m = 1.f - (1.f - amq)*(1.f - amk);
      P2[q*40 + key] = (_Float16)((pe/s)*(1.f - m));
    }
    __syncthreads();
    {
      f32x4 acc = 0.f;
      f16x8 A = *(const f16x8*)(P2 + li*40 + lg*8);
      f16x8 B = *(const f16x8*)(Vt2 + (16*w + li)*40 + lg*8);
      acc = mfma16(A, B, acc);
#pragma unroll
      for (int j = 0; j < 4; ++j)
        outp[(4*lg + j)*264 + 64*h + 16*w + li] = acc[j];
    }
    __syncthreads();
  }
  {
    f32x4 acc[4];
#pragma unroll
    for (int c = 0; c < 4; ++c) acc[c] = 0.f;
    for (int kk = 0; kk < 8; ++kk){
      const float* ap = outp + li*264 + kk*32 + lg*8;
      f32x4 v0 = *(const f32x4*)ap, v1 = *(const f32x4*)(ap + 4);
      f16x8 A;
#pragma unroll
      for (int e = 0; e < 4; ++e){ A[e] = (_Float16)v0[e]; A[e+4] = (_Float16)v1[e]; }
#pragma unroll
      for (int c = 0; c < 4; ++c){
        f16x8 B = *(const f16x8*)(GMOUT + (size_t)(64*w + 16*c + li)*256 + kk*32 + lg*8);
        acc[c] = mfma16(A, B, acc[c]);
      }
    }
#pragma unroll
    for (int c = 0; c < 4; ++c){
      int col = 64*w + 16*c + li;
      float bias = gob[col];
#pragma unroll
      for (int j = 0; j < 4; ++j){
        int q = 4*lg + j;
        float v = (acc[c][j] + bias)*(1.f - em[(size_t)b*64 + q]);
        cat_s[q*520 + 256 + col] = (_Float16)v;
      }
    }
  }
  __syncthreads();
  {
    f32x4 acc[4];
#pragma unroll
    for (int c = 0; c < 4; ++c) acc[c] = 0.f;
    for (int kk = 0; kk < 16; ++kk){
      f16x8 A = *(const f16x8*)(cat_s + li*520 + kk*32 + lg*8);
#pragma unroll
      for (int c = 0; c < 4; ++c){
        f16x8 B = *(const f16x8*)(FC2T + (size_t)(64*w + 16*c + li)*512 + kk*32 + lg*8);
        acc[c] = mfma16(A, B, acc[c]);
      }
    }
#pragma unroll
    for (int c = 0; c < 4; ++c){
      int col = 64*w + 16*c + li;
      float bias = fc2b[col];
#pragma unroll
      for (int j = 0; j < 4; ++j)
        x3_s[(4*lg + j)*264 + col] = (_Float16)fmaxf(acc[c][j] + bias, 0.f);
    }
  }
  __syncthreads();
  {
    const int r0 = (b >> 6)*16, t = b & 63;
    f32x4 acc[12];
#pragma unroll
    for (int cc = 0; cc < 12; ++cc) acc[cc] = 0.f;
    for (int kk = 0; kk < 8; ++kk){
      f16x8 A = *(const f16x8*)(x3_s + li*264 + kk*32 + lg*8);
#pragma unroll
      for (int cc = 0; cc < 12; ++cc){
        int col = (w*12 + cc)*16 + li;
        f16x8 B = *(const f16x8*)(GIHT + (size_t)col*256 + kk*32 + lg*8);
        acc[cc] = mfma16(A, B, acc[cc]);
      }
    }
#pragma unroll
    for (int cc = 0; cc < 12; ++cc){
      int col = (w*12 + cc)*16 + li;
      float bias = gib[col];
#pragma unroll
      for (int j = 0; j < 4; ++j){
        int q = 4*lg + j;
        gi[((size_t)((r0 + q)*64 + t))*768 + col] = acc[cc][j] + bias;
      }
    }
  }
}

// ------------------------------------------------------------------ K3: GRU
// 32 blocks x 16 rows; 256 threads = 4 waves. gi software-pipelined one full
// step ahead (g[t+1] loaded during step t, consumed in step t+1).
__global__ __launch_bounds__(256) void k3_gru(
    const _Float16* __restrict__ WHH, const float* __restrict__ bhh,
    const float* __restrict__ gi, const float* __restrict__ h0,
    float* __restrict__ hs)
{
  const int rb = blockIdx.x;
  const int row0 = rb * 16;
  const int tid = threadIdx.x;
  const int w = tid >> 6, lg = (tid >> 4) & 3, li = tid & 15;

  extern __shared__ char smem3[];
  _Float16* hf16 = (_Float16*)smem3;
  float* hf32 = (float*)(smem3 + 8448);
  float* gh   = (float*)(smem3 + 8448 + 16640);
  float* bhs  = (float*)(smem3 + 8448 + 16640 + 49664);

  for (int idx = tid; idx < 768; idx += 256) bhs[idx] = bhh[idx];
  for (int idx = tid; idx < 4096; idx += 256){
    int r = idx >> 8, d = idx & 255;
    float v = h0[(size_t)(row0 + r)*256 + d];
    hf32[r*260 + d] = v;
    hf16[r*264 + d] = (_Float16)v;
  }
  __syncthreads();

  const int er = tid >> 4;
  const int d0 = (tid & 15) * 16;
  const float* gbase = gi + ((size_t)(row0 + er)*64)*768 + d0;

  // preload g[0]
  f32x4 gr[4], gz[4], gn[4];
#pragma unroll
  for (int v = 0; v < 4; ++v){
    gr[v] = *(const f32x4*)(gbase + v*4);
    gz[v] = *(const f32x4*)(gbase + 256 + v*4);
    gn[v] = *(const f32x4*)(gbase + 512 + v*4);
  }

  for (int t = 0; t < 64; ++t){
    // prefetch g[t+1] (clamped on last iter) — covered by the whole step
    const float* gp = gbase + (size_t)((t < 63) ? t+1 : t)*768;
    f32x4 nr[4], nz[4], nn[4];
#pragma unroll
    for (int v = 0; v < 4; ++v){
      nr[v] = *(const f32x4*)(gp + v*4);
      nz[v] = *(const f32x4*)(gp + 256 + v*4);
      nn[v] = *(const f32x4*)(gp + 512 + v*4);
    }
    // A fragments: h (16 rows x 256 k) as f16 from LDS
    f16x8 a[8];
#pragma unroll
    for (int kk = 0; kk < 8; ++kk)
      a[kk] = *(const f16x8*)(hf16 + li*264 + kk*32 + lg*8);
    // gh = h @ w_hh : wave w covers cols [w*192, w*192+192), 12 tiles x 8 k
    f32x4 acc[12];
#pragma unroll
    for (int c = 0; c < 12; ++c) acc[c] = 0.f;
#pragma unroll
    for (int c = 0; c < 12; ++c){
      const _Float16* bp = WHH + (size_t)(w*192 + c*16 + li)*256 + lg*8;
#pragma unroll
      for (int kk = 0; kk < 8; ++kk)
        acc[c] = mfma16(a[kk], *(const f16x8*)(bp + kk*32), acc[c]);
    }
#pragma unroll
    for (int c = 0; c < 12; ++c){
      int col = w*192 + c*16 + li;
#pragma unroll
      for (int j = 0; j < 4; ++j)
        gh[(4*lg + j)*776 + col] = acc[c][j];
    }
    __syncthreads();
    // elementwise GRU cell: thread -> (er, dims d0..d0+15), uses g[t] regs
    {
      float* hp32 = hf32 + er*260 + d0;
      float* hsp  = hs + ((size_t)(rb*64 + t)*16 + er)*256 + d0;
      f16x8 hv8[2];
#pragma unroll
      for (int v = 0; v < 4; ++v){
        f32x4 xr = *(const f32x4*)(gh + er*776 +       d0 + v*4);
        f32x4 xz = *(const f32x4*)(gh + er*776 + 256 + d0 + v*4);
        f32x4 xn = *(const f32x4*)(gh + er*776 + 512 + d0 + v*4);
        f32x4 hold = *(const f32x4*)(hp32 + v*4);
        f32x4 hout;
#pragma unroll
        for (int e = 0; e < 4; ++e){
          int d = d0 + v*4 + e;
          float rr_ = 1.f/(1.f + expf(-(gr[v][e] + xr[e] + bhs[d])));
          float zz  = 1.f/(1.f + expf(-(gz[v][e] + xz[e] + bhs[256 + d])));
          float nn_ = tanhf(gn[v][e] + rr_*(xn[e] + bhs[512 + d]));
          float hv = (1.f - zz)*nn_ + zz*hold[e];
          hout[e] = hv;
          int sl = v*4 + e;
          hv8[sl >> 3][sl & 7] = (_Float16)hv;
        }
        *(f32x4*)(hp32 + v*4) = hout;
        *(f32x4*)(hsp + v*4)  = hout;
      }
      *(f16x8*)(hf16 + er*264 + d0)     = hv8[0];
      *(f16x8*)(hf16 + er*264 + d0 + 8) = hv8[1];
    }
    __syncthreads();
    // rotate pipeline registers
#pragma unroll
    for (int v = 0; v < 4; ++v){ gr[v] = nr[v]; gz[v] = nz[v]; gn[v] = nn[v]; }
  }
}

// ------------------------------------------------------------------ K4: q out
__global__ __launch_bounds__(256) void k4_q(
    const _Float16* __restrict__ FC3T, const float* __restrict__ fc3b,
    const float* __restrict__ em, const float* __restrict__ hs, float* __restrict__ qo)
{
  const int tid = threadIdx.x;
  const int w = tid >> 6, lg = (tid >> 4) & 3, li = tid & 15;
  const int rb = blockIdx.x*64 + 16*w;
  f32x4 acc[2];
#pragma unroll
  for (int c = 0; c < 2; ++c) acc[c] = 0.f;
  for (int kk = 0; kk < 8; ++kk){
    const float* ap = hs + (size_t)(rb + li)*256 + kk*32 + lg*8;
    f32x4 v0 = *(const f32x4*)ap, v1 = *(const f32x4*)(ap + 4);
    f16x8 A;
#pragma unroll
    for (int e = 0; e < 4; ++e){ A[e] = (_Float16)v0[e]; A[e+4] = (_Float16)v1[e]; }
#pragma unroll
    for (int c = 0; c < 2; ++c){
      f16x8 B = *(const f16x8*)(FC3T + (size_t)(16*c + li)*256 + kk*32 + lg*8);
      acc[c] = mfma16(A, B, acc[c]);
    }
  }
#pragma unroll
  for (int c = 0; c < 2; ++c){
    int col = 16*c + li;
    float bias = fc3b[col];
#pragma unroll
    for (int j = 0; j < 4; ++j){
      int row = rb + 4*lg + j;
      float am = em[(size_t)(row >> 4)*64 + (row & 15)];
      qo[(size_t)row*32 + col] = (acc[c][j] + bias)*(1.f - am);
    }
  }
}

// --------------------------------------------------------------------- launch
extern "C" void kernel_launch(void* const* d_in, const int* in_sizes, int n_in,
                              void* d_out, int out_size, void* d_ws, size_t ws_size,
                              hipStream_t stream)
{
  // ws layout (bytes)
  constexpr size_t OFF_FC1T   = 0;
  constexpr size_t OFF_MSG1T  = 49152;
  constexpr size_t OFF_AINT   = 98304;
  constexpr size_t OFF_LINT   = 491520;
  constexpr size_t OFF_AOUTT  = 884736;
  constexpr size_t OFF_LOUTT  = 1015808;
  constexpr size_t OFF_GMINT  = 1146880;
  constexpr size_t OFF_GMOUTT = 1540096;
  constexpr size_t OFF_FC2T   = 1671168;
  constexpr size_t OFF_GIHT   = 1933312;
  constexpr size_t OFF_GHHT   = 2326528;
  constexpr size_t OFF_FC3T   = 2719744;
  constexpr size_t OFF_G1T    = 2736128;   // f16 hi+lo pair
  constexpr size_t OFF_GINT   = 2834432;   // pair
  constexpr size_t OFF_WVEFF  = 3620864;   // pair
  constexpr size_t OFF_BEFF   = 3637248;
  constexpr size_t OFF_GATE   = 3637504;   // 131072 -> ends 3768576
  constexpr size_t OFF_X2     = 3768576;   // 33554432
  constexpr size_t OFF_X2M    = 37323008;  // 33554432
  constexpr size_t OFF_GI     = 70877440;  // 100663296 -> ends 171540736
  // gate temps (f32; consumed by k1gb BEFORE X2/X2M/GI are written -> alias)
  constexpr size_t OFF_KG     = 3768576;   // 2048*64*256*4 = 134217728
  constexpr size_t OFF_QG     = 137986304; // 2048*16*256*4 = 33554432
  constexpr size_t OFF_V2G    = 171540736; // 2048*64*16*4  = 8388608
  constexpr size_t NEED       = 179929344;
  if (ws_size < NEED) return;

  char* ws = (char*)d_ws;
  const float* ent = (const float*)d_in[0];
  const float* om  = (const float*)d_in[1];
  const float* em  = (const float*)d_in[2];

  WJobs jb{};
  int nj = 0;
  auto addj = [&](int src_idx, size_t off, int K, int N, int m){
    jb.src[nj] = (const float*)d_in[src_idx]; jb.off[nj] = (unsigned)off;
    jb.K[nj] = K; jb.N[nj] = N; jb.mode[nj] = m; ++nj;
  };
  addj(4,  OFF_FC1T,   96, 256, 0);
  addj(17, OFF_MSG1T,  96, 256, 0);
  addj(6,  OFF_AINT,  256, 768, 0);
  addj(19, OFF_LINT,  256, 768, 0);
  addj(7,  OFF_AOUTT, 256, 256, 0);
  addj(20, OFF_LOUTT, 256, 256, 0);
  addj(22, OFF_GMINT, 256, 768, 0);
  addj(23, OFF_GMOUTT,256, 256, 0);
  addj(9,  OFF_FC2T,  512, 256, 0);
  addj(11, OFF_GIHT,  256, 768, 0);
  addj(12, OFF_GHHT,  256, 768, 0);
  addj(15, OFF_FC3T,  256,  32, 0);
  addj(28, OFF_G1T,    96, 256, 1);
  addj(25, OFF_GINT,  256, 768, 1);
  k0_conv<<<dim3(96, nj), 256, 0, stream>>>(jb, ws);

  k0w_gate<<<1, 256, 0, stream>>>(
      (const float*)d_in[26], (const float*)d_in[30],
      (const float*)d_in[27], (const float*)d_in[25],
      (_Float16*)(ws + OFF_WVEFF), (float*)(ws + OFF_BEFF));

  constexpr int SM0 = 69888, SMA = 67584, SM3 = 77824;
  (void)hipFuncSetAttribute(reinterpret_cast<const void*>(&k1_branch<0>),
                            hipFuncAttributeMaxDynamicSharedMemorySize, SM0);
  (void)hipFuncSetAttribute(reinterpret_cast<const void*>(&k1ga),
                            hipFuncAttributeMaxDynamicSharedMemorySize, SMA);
  (void)hipFuncSetAttribute(reinterpret_cast<const void*>(&k3_gru),
                            hipFuncAttributeMaxDynamicSharedMemorySize, SM3);

  float* qout = (float*)d_out;
  float* hsout = qout + 1048576;
  float* gout = qout + 9437184;

  // gate branch first (its temps alias X2/X2M/GI regions, consumed by k1gb)
  k1ga<<<2048, 512, SMA, stream>>>(ent,
      (const _Float16*)(ws + OFF_G1T), (const float*)d_in[29],
      (const _Float16*)(ws + OFF_GINT),
      (const _Float16*)(ws + OFF_WVEFF),
      (float*)(ws + OFF_KG), (float*)(ws + OFF_QG), (float*)(ws + OFF_V2G));
  k1gb<<<2048, 256, 0, stream>>>(om, em,
      (const float*)(ws + OFF_KG), (const float*)(ws + OFF_QG),
      (const float*)(ws + OFF_V2G),
      (const float*)(ws + OFF_BEFF), (const float*)d_in[31],
      gout, (float*)(ws + OFF_GATE));

  k1_branch<0><<<2048, 256, SM0, stream>>>(ent, om, em,
      (const _Float16*)(ws + OFF_FC1T),  (const float*)d_in[5],
      (const _Float16*)(ws + OFF_AINT),
      (const _Float16*)(ws + OFF_AOUTT), (const float*)d_in[8],
      (float*)(ws + OFF_X2));
  k1_branch<0><<<2048, 256, SM0, stream>>>(ent, om, em,
      (const _Float16*)(ws + OFF_MSG1T), (const float*)d_in[18],
      (const _Float16*)(ws + OFF_LINT),
      (const _Float16*)(ws + OFF_LOUTT), (const float*)d_in[21],
      (float*)(ws + OFF_X2M));

  k2_global<<<2048, 256, 0, stream>>>(em,
      (const float*)(ws + OFF_X2), (const float*)(ws + OFF_X2M),
      (const float*)(ws + OFF_GATE),
      (const _Float16*)(ws + OFF_GMINT), (const _Float16*)(ws + OFF_GMOUTT), (const float*)d_in[24],
      (const _Float16*)(ws + OFF_FC2T), (const float*)d_in[10],
      (const _Float16*)(ws + OFF_GIHT), (const float*)d_in[13],
      (float*)(ws + OFF_GI));

  k3_gru<<<32, 256, SM3, stream>>>(
      (const _Float16*)(ws + OFF_GHHT), (const float*)d_in[14],
      (const float*)(ws + OFF_GI), (const float*)d_in[3], hsout);

  k4_q<<<512, 256, 0, stream>>>(
      (const _Float16*)(ws + OFF_FC3T), (const float*)d_in[16],
      em, hsout, qout);
}

// Round 9
// 1806.652 us; speedup vs baseline: 1.1808x; 1.1808x over previous
//
#include <hip/hip_runtime.h>

// EntityAttentionRNNMsgAgent — fused MI355X implementation.
// r9 = revert to r3 (best measured, 1807us) + merge the two k1_branch
// launches into one 4096-block dispatch (tail-fill; same-stream kernels
// serialize strictly, so the two 2048-block launches wasted one drain tail).
// Stages:
//  K0:  transpose all weights to f16 [N][K] (gate branch: hi/lo split pair)
//  K0w: gate-tail collapse: Weff = Wout@Wg2, Wveff (256x8), beff — f32, 1 block
//  K1<0> merged: x2 main + x2_msg (br = blockIdx.x>>11 selects weights/output)
//  K1g: gate branch, algebraically reduced (no V / PV / out-proj): x1,Q,K,
//       logits in split-2 f16 + f32 P.v2 contraction -> og + gate flag
//  K2:  gated_msg, global attention, fc2, gru-input GEMM (gi); reads gate flag
//  K3:  64-step GRU, row-partitioned (32 blocks x 16 rows), h resident in LDS
//  K4:  q = hs @ fc3 + b, masked

#define DEV __device__ __forceinline__

typedef _Float16 f16x8 __attribute__((ext_vector_type(8)));
typedef float    f32x4 __attribute__((ext_vector_type(4)));

DEV f32x4 mfma16(f16x8 a, f16x8 b, f32x4 c){
  return __builtin_amdgcn_mfma_f32_16x16x32_f16(a, b, c, 0, 0, 0);
}

// A/B fragment pair for optional split-precision (MODE=1: value = hi + lo)
template<int MODE> struct AB {
  f16x8 hi, lo;
  DEV void mf(const AB& b, f32x4& c) const {
    if constexpr (MODE){
      c = mfma16(lo, b.hi, c);
      c = mfma16(hi, b.lo, c);
    }
    c = mfma16(hi, b.hi, c);
  }
};

template<int MODE> DEV AB<MODE> ldW(const _Float16* p, int losz){
  AB<MODE> r; r.hi = *(const f16x8*)p;
  if constexpr (MODE) r.lo = *(const f16x8*)(p + losz);
  return r;
}
template<int MODE> DEV AB<MODE> ldL(const _Float16* ph, const _Float16* pl){
  AB<MODE> r; r.hi = *(const f16x8*)ph;
  if constexpr (MODE) r.lo = *(const f16x8*)pl;
  return r;
}
template<int MODE> DEV AB<MODE> ldF(const float* p){
  AB<MODE> r;
  f32x4 v0 = *(const f32x4*)p, v1 = *(const f32x4*)(p + 4);
#pragma unroll
  for (int i = 0; i < 4; ++i){
    float a = v0[i], b = v1[i];
    _Float16 ah = (_Float16)a, bh = (_Float16)b;
    r.hi[i] = ah; r.hi[i+4] = bh;
    if constexpr (MODE){
      r.lo[i]   = (_Float16)(a - (float)ah);
      r.lo[i+4] = (_Float16)(b - (float)bh);
    }
  }
  return r;
}
template<int MODE> DEV void stL(_Float16* ph, _Float16* pl, int idx, float v){
  _Float16 h = (_Float16)v;
  ph[idx] = h;
  if constexpr (MODE) pl[idx] = (_Float16)(v - (float)h);
}

// ---------------------------------------------------------------- K0: weights
struct WJobs {
  const float* src[15];
  unsigned off[15];
  int K[15], N[15], mode[15];
};

__global__ __launch_bounds__(256) void k0_conv(WJobs jb, char* ws){
  const int job = blockIdx.y;
  const int K = jb.K[job], N = jb.N[job];
  const int total = K * N;
  _Float16* dh = (_Float16*)(ws + jb.off[job]);
  const float* src = jb.src[job];
  const int m = jb.mode[job];
  for (int idx = blockIdx.x*256 + threadIdx.x; idx < total; idx += gridDim.x*256){
    int n = idx / K, k = idx - n*K;
    float v = src[(size_t)k*N + n];
    _Float16 h = (_Float16)v;
    dh[idx] = h;
    if (m) dh[total + idx] = (_Float16)(v - (float)h);
  }
}

// ------------------------------------------------- K0w: gate-tail precompute
// Weff = gate_out_w @ gatefc2_w (256x2); beff = gate_out_b . gatefc2_w;
// Wveff[j, h*2+c] = sum_d gate_in_w[j, 512+h*64+d] * Weff[h*64+d, c]
// stored as f16 hi/lo pair, MFMA-B layout [n=16 (8 used)][k=256].
__global__ __launch_bounds__(256) void k0w_gate(
    const float* __restrict__ Wout, const float* __restrict__ Wg2,
    const float* __restrict__ bo,   const float* __restrict__ Win,
    _Float16* __restrict__ wveff, float* __restrict__ beff)
{
  __shared__ float weff_s[256*2];
  const int tid = threadIdx.x;
  {
    float a0 = 0.f, a1 = 0.f;
    const float* wr = Wout + (size_t)tid*256;
    for (int f = 0; f < 256; ++f){ float x = wr[f]; a0 += x*Wg2[2*f]; a1 += x*Wg2[2*f+1]; }
    weff_s[tid*2] = a0; weff_s[tid*2+1] = a1;
  }
  if (tid < 2){
    float s = 0.f;
    for (int f = 0; f < 256; ++f) s += bo[f]*Wg2[2*f + tid];
    beff[tid] = s;
  }
  __syncthreads();
  {
    const int j = tid;
    for (int n = 0; n < 16; ++n){
      float v = 0.f;
      if (n < 8){
        int h = n >> 1, c = n & 1;
        const float* wr = Win + (size_t)j*768 + 512 + h*64;
        const float* we = weff_s + (h*64)*2 + c;
        for (int d = 0; d < 64; ++d) v += wr[d]*we[2*d];
      }
      _Float16 hi = (_Float16)v;
      wveff[n*256 + j] = hi;
      wveff[16*256 + n*256 + j] = (_Float16)(v - (float)hi);
    }
  }
}

// ------------------------------------------------------- K1: branch attention
// Merged: 4096 blocks; br = blockIdx.x>>11 selects {main, msg} weight set.
// One block per (branch, batch item). 256 threads = 4 waves.
template<int MODE>
__global__ __launch_bounds__(256) void k1_branch(
    const float* __restrict__ ent, const float* __restrict__ om, const float* __restrict__ em,
    const _Float16* __restrict__ W1a, const float* __restrict__ b1a,
    const _Float16* __restrict__ WINa,
    const _Float16* __restrict__ WOUTa, const float* __restrict__ boa,
    float* __restrict__ x2outa,
    const _Float16* __restrict__ W1b, const float* __restrict__ b1b,
    const _Float16* __restrict__ WINb,
    const _Float16* __restrict__ WOUTb, const float* __restrict__ bob,
    float* __restrict__ x2outb)
{
  constexpr int W1SZ = 96*256, WINSZ = 256*768, WOUTSZ = 256*256;
  const int br = blockIdx.x >> 11;
  const int b = blockIdx.x & 2047;
  const _Float16* W1   = br ? W1b   : W1a;
  const float*    b1   = br ? b1b   : b1a;
  const _Float16* WIN  = br ? WINb  : WINa;
  const _Float16* WOUT = br ? WOUTb : WOUTa;
  const float*    bo   = br ? bob   : boa;
  float*          x2out= br ? x2outb: x2outa;

  const int tid = threadIdx.x;
  const int w = tid >> 6, lg = (tid >> 4) & 3, li = tid & 15;

  extern __shared__ char smem[];
  char* sp = smem;
  _Float16* x1h = (_Float16*)sp; sp += 64*264*2;
  _Float16* x1l = x1h; if constexpr (MODE){ x1l = (_Float16*)sp; sp += 64*264*2; }
  _Float16* Kh  = (_Float16*)sp; sp += 64*72*2;
  _Float16* Kl  = Kh;  if constexpr (MODE){ Kl = (_Float16*)sp; sp += 64*72*2; }
  _Float16* Vh  = (_Float16*)sp; sp += 64*72*2;   // V transposed: [dim][key]
  _Float16* Vl  = Vh;  if constexpr (MODE){ Vl = (_Float16*)sp; sp += 64*72*2; }
  _Float16* Qh  = (_Float16*)sp; sp += 16*72*2;
  _Float16* Ql  = Qh;  if constexpr (MODE){ Ql = (_Float16*)sp; sp += 16*72*2; }
  float*    lgs = (float*)sp;    sp += 16*72*4;
  _Float16* Ph  = (_Float16*)sp; sp += 16*72*2;
  _Float16* Pl  = Ph;  if constexpr (MODE){ Pl = (_Float16*)sp; sp += 16*72*2; }
  float*   outp = (float*)sp;    sp += 16*264*4;

  // ---- phase 1: x1 = relu(ent @ W1 + b1)   (M=64,K=96,N=256)
  {
    f32x4 acc[4][4];
#pragma unroll
    for (int r = 0; r < 4; ++r)
#pragma unroll
      for (int c = 0; c < 4; ++c) acc[r][c] = 0.f;
#pragma unroll
    for (int kk = 0; kk < 3; ++kk){
      AB<MODE> a[4];
#pragma unroll
      for (int r = 0; r < 4; ++r)
        a[r] = ldF<MODE>(ent + ((size_t)b*64 + 16*r + li)*96 + kk*32 + lg*8);
#pragma unroll
      for (int c = 0; c < 4; ++c){
        AB<MODE> bb = ldW<MODE>(W1 + (size_t)(64*w + 16*c + li)*96 + kk*32 + lg*8, W1SZ);
#pragma unroll
        for (int r = 0; r < 4; ++r) a[r].mf(bb, acc[r][c]);
      }
    }
#pragma unroll
    for (int c = 0; c < 4; ++c){
      int col = 64*w + 16*c + li;
      float bias = b1[col];
#pragma unroll
      for (int r = 0; r < 4; ++r)
#pragma unroll
        for (int j = 0; j < 4; ++j){
          float v = fmaxf(acc[r][c][j] + bias, 0.f);
          stL<MODE>(x1h, x1l, (16*r + 4*lg + j)*264 + col, v);
        }
    }
  }
  __syncthreads();

  // ---- phase 2: per-head attention
  for (int h = 0; h < 4; ++h){
    { // K_h
      f32x4 acc[4];
#pragma unroll
      for (int c = 0; c < 4; ++c) acc[c] = 0.f;
      for (int kk = 0; kk < 8; ++kk){
        int ao = (16*w + li)*264 + kk*32 + lg*8;
        AB<MODE> a = ldL<MODE>(x1h + ao, x1l + ao);
#pragma unroll
        for (int c = 0; c < 4; ++c){
          AB<MODE> bb = ldW<MODE>(WIN + (size_t)(256 + 64*h + 16*c + li)*256 + kk*32 + lg*8, WINSZ);
          a.mf(bb, acc[c]);
        }
      }
#pragma unroll
      for (int c = 0; c < 4; ++c)
#pragma unroll
        for (int j = 0; j < 4; ++j)
          stL<MODE>(Kh, Kl, (16*w + 4*lg + j)*72 + 16*c + li, acc[c][j]);
    }
    { // V_h (stored transposed)
      f32x4 acc[4];
#pragma unroll
      for (int c = 0; c < 4; ++c) acc[c] = 0.f;
      for (int kk = 0; kk < 8; ++kk){
        int ao = (16*w + li)*264 + kk*32 + lg*8;
        AB<MODE> a = ldL<MODE>(x1h + ao, x1l + ao);
#pragma unroll
        for (int c = 0; c < 4; ++c){
          AB<MODE> bb = ldW<MODE>(WIN + (size_t)(512 + 64*h + 16*c + li)*256 + kk*32 + lg*8, WINSZ);
          a.mf(bb, acc[c]);
        }
      }
#pragma unroll
      for (int c = 0; c < 4; ++c)
#pragma unroll
        for (int j = 0; j < 4; ++j)
          stL<MODE>(Vh, Vl, (16*c + li)*72 + 16*w + 4*lg + j, acc[c][j]);
    }
    { // Q_h
      f32x4 acc = 0.f;
      for (int kk = 0; kk < 8; ++kk){
        int ao = li*264 + kk*32 + lg*8;
        AB<MODE> a = ldL<MODE>(x1h + ao, x1l + ao);
        AB<MODE> bb = ldW<MODE>(WIN + (size_t)(64*h + 16*w + li)*256 + kk*32 + lg*8, WINSZ);
        a.mf(bb, acc);
      }
#pragma unroll
      for (int j = 0; j < 4; ++j)
        stL<MODE>(Qh, Ql, (4*lg + j)*72 + 16*w + li, acc[j]);
    }
    __syncthreads();
    { // logits
      f32x4 acc = 0.f;
#pragma unroll
      for (int kk = 0; kk < 2; ++kk){
        int ao = li*72 + kk*32 + lg*8;
        AB<MODE> a = ldL<MODE>(Qh + ao, Ql + ao);
        int bo_ = (16*w + li)*72 + kk*32 + lg*8;
        AB<MODE> bb = ldL<MODE>(Kh + bo_, Kl + bo_);
        a.mf(bb, acc);
      }
#pragma unroll
      for (int j = 0; j < 4; ++j){
        int q = 4*lg + j, key = 16*w + li;
        float v = acc[j] * 0.125f;
        float m = om[((size_t)b*64 + q)*64 + key];
        if (m > 0.f) v = -1e9f;
        lgs[q*72 + key] = v;
      }
    }
    __syncthreads();
    { // softmax
      int q = tid >> 4, i16 = tid & 15;
      float pv[4], mx = -3e38f;
#pragma unroll
      for (int u = 0; u < 4; ++u){ pv[u] = lgs[q*72 + i16 + 16*u]; mx = fmaxf(mx, pv[u]); }
#pragma unroll
      for (int d = 1; d < 16; d <<= 1) mx = fmaxf(mx, __shfl_xor(mx, d, 16));
      float s = 0.f;
#pragma unroll
      for (int u = 0; u < 4; ++u){ pv[u] = expf(pv[u] - mx); s += pv[u]; }
#pragma unroll
      for (int d = 1; d < 16; d <<= 1) s += __shfl_xor(s, d, 16);
#pragma unroll
      for (int u = 0; u < 4; ++u){
        int key = i16 + 16*u;
        float m = om[((size_t)b*64 + q)*64 + key];
        stL<MODE>(Ph, Pl, q*72 + key, (pv[u]/s)*(1.f - m));
      }
    }
    __syncthreads();
    { // out_h = P @ V_h
      f32x4 acc = 0.f;
#pragma unroll
      for (int kk = 0; kk < 2; ++kk){
        int ao = li*72 + kk*32 + lg*8;
        AB<MODE> a = ldL<MODE>(Ph + ao, Pl + ao);
        int bo_ = (16*w + li)*72 + kk*32 + lg*8;
        AB<MODE> bb = ldL<MODE>(Vh + bo_, Vl + bo_);
        a.mf(bb, acc);
      }
#pragma unroll
      for (int j = 0; j < 4; ++j)
        outp[(4*lg + j)*264 + 64*h + 16*w + li] = acc[j];
    }
    __syncthreads();
  }

  // ---- phase 3: out-proj + bias + post-mask
  {
    f32x4 acc[4];
#pragma unroll
    for (int c = 0; c < 4; ++c) acc[c] = 0.f;
    for (int kk = 0; kk < 8; ++kk){
      AB<MODE> a = ldF<MODE>(outp + li*264 + kk*32 + lg*8);
#pragma unroll
      for (int c = 0; c < 4; ++c){
        AB<MODE> bb = ldW<MODE>(WOUT + (size_t)(64*w + 16*c + li)*256 + kk*32 + lg*8, WOUTSZ);
        a.mf(bb, acc[c]);
      }
    }
#pragma unroll
    for (int c = 0; c < 4; ++c){
      int col = 64*w + 16*c + li;
      float bias = bo[col];
#pragma unroll
      for (int j = 0; j < 4; ++j){
        int q = 4*lg + j;
        float v = (acc[c][j] + bias) * (1.f - em[(size_t)b*64 + q]);
        x2out[((size_t)b*16 + q)*256 + col] = v;
      }
    }
  }
}

// --------------------------------------------- K1g: reduced gate branch
// 512 threads = 8 waves, one block per batch item.
// x1/Q/K/logits in split-2 f16 (f32 fidelity); P.v2 contraction in f32.
__global__ __launch_bounds__(512) void k1_gate(
    const float* __restrict__ ent, const float* __restrict__ om, const float* __restrict__ em,
    const _Float16* __restrict__ W1, const float* __restrict__ b1,
    const _Float16* __restrict__ WIN,
    const _Float16* __restrict__ WVEFF,
    const float* __restrict__ beff, const float* __restrict__ gb2,
    float* __restrict__ og, float* __restrict__ gate)
{
  constexpr int W1SZ = 96*256, WINSZ = 256*768, WVSZ = 16*256;
  const int b = blockIdx.x;
  const int tid = threadIdx.x;
  const int w = tid >> 6, lg = (tid >> 4) & 3, li = tid & 15;

  extern __shared__ char smem[];
  char* sp = smem;
  _Float16* x1h = (_Float16*)sp; sp += 64*264*2;
  _Float16* x1l = (_Float16*)sp; sp += 64*264*2;
  _Float16* Kh  = (_Float16*)sp; sp += 64*72*2;
  _Float16* Kl  = (_Float16*)sp; sp += 64*72*2;
  _Float16* Qh  = (_Float16*)sp; sp += 16*264*2;
  _Float16* Ql  = (_Float16*)sp; sp += 16*264*2;
  float*    lgs = (float*)sp;    sp += 16*72*4;
  float*    Ps  = (float*)sp;    sp += 16*66*4;
  float*    v2s = (float*)sp;    sp += 64*18*4;
  float*  ogacc = (float*)sp;    sp += 32*4;

  // ---- phase 1: x1 = relu(ent @ W1 + b1); wave w -> m-tile w>>1, 8 n-tiles
  {
    const int mt = w >> 1;
    f32x4 acc[8];
#pragma unroll
    for (int c = 0; c < 8; ++c) acc[c] = 0.f;
#pragma unroll
    for (int kk = 0; kk < 3; ++kk){
      AB<1> a = ldF<1>(ent + ((size_t)b*64 + mt*16 + li)*96 + kk*32 + lg*8);
#pragma unroll
      for (int c = 0; c < 8; ++c){
        int nt = (w & 1)*8 + c;
        AB<1> bb = ldW<1>(W1 + (size_t)(nt*16 + li)*96 + kk*32 + lg*8, W1SZ);
        a.mf(bb, acc[c]);
      }
    }
#pragma unroll
    for (int c = 0; c < 8; ++c){
      int col = ((w & 1)*8 + c)*16 + li;
      float bias = b1[col];
#pragma unroll
      for (int j = 0; j < 4; ++j){
        float v = fmaxf(acc[c][j] + bias, 0.f);
        stL<1>(x1h, x1l, (mt*16 + 4*lg + j)*264 + col, v);
      }
    }
  }
  if (tid < 32) ogacc[tid] = 0.f;
  __syncthreads();

  // ---- phase 2: Qfull = x1[0:16] @ Wq (16 n-tiles), v2 = x1 @ Wveff (4 m-tiles)
  {
#pragma unroll
    for (int s = 0; s < 2; ++s){
      int nt = w + s*8;
      f32x4 acc = 0.f;
      for (int kk = 0; kk < 8; ++kk){
        int ao = li*264 + kk*32 + lg*8;
        AB<1> a = ldL<1>(x1h + ao, x1l + ao);
        AB<1> bb = ldW<1>(WIN + (size_t)(nt*16 + li)*256 + kk*32 + lg*8, WINSZ);
        a.mf(bb, acc);
      }
#pragma unroll
      for (int j = 0; j < 4; ++j)
        stL<1>(Qh, Ql, (4*lg + j)*264 + nt*16 + li, acc[j]);
    }
    if (w < 4){   // v2 m-tile w
      f32x4 acc = 0.f;
      for (int kk = 0; kk < 8; ++kk){
        int ao = (w*16 + li)*264 + kk*32 + lg*8;
        AB<1> a = ldL<1>(x1h + ao, x1l + ao);
        AB<1> bb = ldW<1>(WVEFF + (size_t)li*256 + kk*32 + lg*8, WVSZ);
        a.mf(bb, acc);
      }
#pragma unroll
      for (int j = 0; j < 4; ++j)
        v2s[(w*16 + 4*lg + j)*18 + li] = acc[j];
    }
  }
  __syncthreads();

  // ---- head loop
  for (int h = 0; h < 4; ++h){
    { // K_h: wave w -> m-tile w>>1, 2 n-tiles
      const int mt = w >> 1;
      f32x4 acc[2];
      acc[0] = 0.f; acc[1] = 0.f;
      for (int kk = 0; kk < 8; ++kk){
        int ao = (mt*16 + li)*264 + kk*32 + lg*8;
        AB<1> a = ldL<1>(x1h + ao, x1l + ao);
#pragma unroll
        for (int c = 0; c < 2; ++c){
          int nt = (w & 1)*2 + c;
          AB<1> bb = ldW<1>(WIN + (size_t)(256 + h*64 + nt*16 + li)*256 + kk*32 + lg*8, WINSZ);
          a.mf(bb, acc[c]);
        }
      }
#pragma unroll
      for (int c = 0; c < 2; ++c){
        int colb = ((w & 1)*2 + c)*16 + li;
#pragma unroll
        for (int j = 0; j < 4; ++j)
          stL<1>(Kh, Kl, (mt*16 + 4*lg + j)*72 + colb, acc[c][j]);
      }
    }
    __syncthreads();
    if (w < 4){ // logits: keys 16w..16w+15
      f32x4 acc = 0.f;
#pragma unroll
      for (int kk = 0; kk < 2; ++kk){
        int ao = li*264 + h*64 + kk*32 + lg*8;
        AB<1> a = ldL<1>(Qh + ao, Ql + ao);
        int bo_ = (16*w + li)*72 + kk*32 + lg*8;
        AB<1> bb = ldL<1>(Kh + bo_, Kl + bo_);
        a.mf(bb, acc);
      }
#pragma unroll
      for (int j = 0; j < 4; ++j){
        int q = 4*lg + j, key = 16*w + li;
        float v = acc[j] * 0.125f;
        float m = om[((size_t)b*64 + q)*64 + key];
        if (m > 0.f) v = -1e9f;
        lgs[q*72 + key] = v;
      }
    }
    __syncthreads();
    if (tid < 256){ // softmax
      int q = tid >> 4, i16 = tid & 15;
      float pv[4], mx = -3e38f;
#pragma unroll
      for (int u = 0; u < 4; ++u){ pv[u] = lgs[q*72 + i16 + 16*u]; mx = fmaxf(mx, pv[u]); }
#pragma unroll
      for (int d = 1; d < 16; d <<= 1) mx = fmaxf(mx, __shfl_xor(mx, d, 16));
      float s = 0.f;
#pragma unroll
      for (int u = 0; u < 4; ++u){ pv[u] = expf(pv[u] - mx); s += pv[u]; }
#pragma unroll
      for (int d = 1; d < 16; d <<= 1) s += __shfl_xor(s, d, 16);
#pragma unroll
      for (int u = 0; u < 4; ++u){
        int key = i16 + 16*u;
        float m = om[((size_t)b*64 + q)*64 + key];
        Ps[q*66 + key] = (pv[u]/s)*(1.f - m);
      }
    }
    __syncthreads();
    if (tid < 256){ // og += P_h . v2_h  (f32)
      int q = tid >> 4, l16 = tid & 15;
      float a0 = 0.f, a1 = 0.f;
#pragma unroll
      for (int u = 0; u < 4; ++u){
        int k = l16 + 16*u;
        float p = Ps[q*66 + k];
        a0 += p * v2s[k*18 + h*2];
        a1 += p * v2s[k*18 + h*2 + 1];
      }
#pragma unroll
      for (int d = 1; d < 16; d <<= 1){ a0 += __shfl_xor(a0, d, 16); a1 += __shfl_xor(a1, d, 16); }
      if (l16 == 0){ ogacc[q*2] += a0; ogacc[q*2 + 1] += a1; }
    }
    __syncthreads();
  }
  // epilogue: og + gate
  if (tid < 16){
    int q = tid;
    float am = em[(size_t)b*64 + q];
    float g0 = (1.f - am)*(ogacc[2*q]     + beff[0]) + gb2[0];
    float g1 = (1.f - am)*(ogacc[2*q + 1] + beff[1]) + gb2[1];
    og[((size_t)b*16 + q)*2]     = g0;
    og[((size_t)b*16 + q)*2 + 1] = g1;
    gate[(size_t)b*16 + q] = (g1 > g0) ? 1.f : 0.f;
  }
}

// ----------------------------------------- K2: gate, global attention, fc2, gi
__global__ __launch_bounds__(256) void k2_global(
    const float* __restrict__ em,
    const float* __restrict__ x2, const float* __restrict__ x2m,
    const float* __restrict__ gate,
    const _Float16* __restrict__ GMIN, const _Float16* __restrict__ GMOUT, const float* __restrict__ gob,
    const _Float16* __restrict__ FC2T, const float* __restrict__ fc2b,
    const _Float16* __restrict__ GIHT, const float* __restrict__ gib,
    float* __restrict__ gi)
{
  const int b = blockIdx.x;
  const int tid = threadIdx.x;
  const int w = tid >> 6, lg = (tid >> 4) & 3, li = tid & 15;

  __shared__ float gate_s[16];
  __shared__ __align__(16) _Float16 gm_s[16*264];
  __shared__ __align__(16) _Float16 Q2[16*72];
  __shared__ __align__(16) _Float16 K2s[16*72];
  __shared__ __align__(16) _Float16 Vt2[64*40];
  __shared__ float lg2[16*24];
  __shared__ __align__(16) _Float16 P2[16*40];
  __shared__ __align__(16) float outp[16*264];
  __shared__ __align__(16) _Float16 cat_s[16*520];
  __shared__ __align__(16) _Float16 x3_s[16*264];

  if (tid < 16) gate_s[tid] = gate[(size_t)b*16 + tid];
  __syncthreads();
  for (int idx = tid; idx < 4096; idx += 256){
    int q = idx >> 8, d = idx & 255;
    gm_s[q*264 + d]  = (_Float16)(x2m[((size_t)b*16 + q)*256 + d] * gate_s[q]);
    cat_s[q*520 + d] = (_Float16)(x2[((size_t)b*16 + q)*256 + d]);
  }
  for (int idx = tid; idx < 64*40; idx += 256) Vt2[idx] = (_Float16)0.f;
  for (int idx = tid; idx < 16*40; idx += 256) P2[idx] = (_Float16)0.f;
  __syncthreads();
  for (int h = 0; h < 4; ++h){
    {
      f32x4 aq = 0.f, ak = 0.f, av = 0.f;
      for (int kk = 0; kk < 8; ++kk){
        f16x8 A  = *(const f16x8*)(gm_s + li*264 + kk*32 + lg*8);
        f16x8 Bq = *(const f16x8*)(GMIN + (size_t)(      64*h + 16*w + li)*256 + kk*32 + lg*8);
        f16x8 Bk = *(const f16x8*)(GMIN + (size_t)(256 + 64*h + 16*w + li)*256 + kk*32 + lg*8);
        f16x8 Bv = *(const f16x8*)(GMIN + (size_t)(512 + 64*h + 16*w + li)*256 + kk*32 + lg*8);
        aq = mfma16(A, Bq, aq); ak = mfma16(A, Bk, ak); av = mfma16(A, Bv, av);
      }
#pragma unroll
      for (int j = 0; j < 4; ++j){
        int rw = 4*lg + j, dim = 16*w + li;
        Q2[rw*72 + dim]  = (_Float16)aq[j];
        K2s[rw*72 + dim] = (_Float16)ak[j];
        Vt2[dim*40 + rw] = (_Float16)av[j];
      }
    }
    __syncthreads();
    if (w == 0){
      f32x4 acc = 0.f;
#pragma unroll
      for (int kk = 0; kk < 2; ++kk){
        f16x8 A = *(const f16x8*)(Q2  + li*72 + kk*32 + lg*8);
        f16x8 B = *(const f16x8*)(K2s + li*72 + kk*32 + lg*8);
        acc = mfma16(A, B, acc);
      }
      float amk = em[(size_t)b*64 + li];
#pragma unroll
      for (int j = 0; j < 4; ++j){
        int q = 4*lg + j;
        float amq = em[(size_t)b*64 + q];
        float m = 1.f - (1.f - amq)*(1.f - amk);
        float v = acc[j]*0.125f;
        if (m > 0.f) v = -1e9f;
        lg2[q*24 + li] = v;
      }
    }
    __syncthreads();
    {
      int q = tid >> 4, key = tid & 15;
      float v = lg2[q*24 + key];
      float mx = v;
#pragma unroll
      for (int d = 1; d < 16; d <<= 1) mx = fmaxf(mx, __shfl_xor(mx, d, 16));
      float pe = expf(v - mx);
      float s = pe;
#pragma unroll
      for (int d = 1; d < 16; d <<= 1) s += __shfl_xor(s, d, 16);
      float amq = em[(size_t)b*64 + q], amk = em[(size_t)b*64 + key];
      float m = 1.f - (1.f - amq)*(1.f - amk);
      P2[q*40 + key] = (_Float16)((pe/s)*(1.f - m));
    }
    __syncthreads();
    {
      f32x4 acc = 0.f;
      f16x8 A = *(const f16x8*)(P2 + li*40 + lg*8);
      f16x8 B = *(const f16x8*)(Vt2 + (16*w + li)*40 + lg*8);
      acc = mfma16(A, B, acc);
#pragma unroll
      for (int j = 0; j < 4; ++j)
        outp[(4*lg + j)*264 + 64*h + 16*w + li] = acc[j];
    }
    __syncthreads();
  }
  {
    f32x4 acc[4];
#pragma unroll
    for (int c = 0; c < 4; ++c) acc[c] = 0.f;
    for (int kk = 0; kk < 8; ++kk){
      const float* ap = outp + li*264 + kk*32 + lg*8;
      f32x4 v0 = *(const f32x4*)ap, v1 = *(const f32x4*)(ap + 4);
      f16x8 A;
#pragma unroll
      for (int e = 0; e < 4; ++e){ A[e] = (_Float16)v0[e]; A[e+4] = (_Float16)v1[e]; }
#pragma unroll
      for (int c = 0; c < 4; ++c){
        f16x8 B = *(const f16x8*)(GMOUT + (size_t)(64*w + 16*c + li)*256 + kk*32 + lg*8);
        acc[c] = mfma16(A, B, acc[c]);
      }
    }
#pragma unroll
    for (int c = 0; c < 4; ++c){
      int col = 64*w + 16*c + li;
      float bias = gob[col];
#pragma unroll
      for (int j = 0; j < 4; ++j){
        int q = 4*lg + j;
        float v = (acc[c][j] + bias)*(1.f - em[(size_t)b*64 + q]);
        cat_s[q*520 + 256 + col] = (_Float16)v;
      }
    }
  }
  __syncthreads();
  {
    f32x4 acc[4];
#pragma unroll
    for (int c = 0; c < 4; ++c) acc[c] = 0.f;
    for (int kk = 0; kk < 16; ++kk){
      f16x8 A = *(const f16x8*)(cat_s + li*520 + kk*32 + lg*8);
#pragma unroll
      for (int c = 0; c < 4; ++c){
        f16x8 B = *(const f16x8*)(FC2T + (size_t)(64*w + 16*c + li)*512 + kk*32 + lg*8);
        acc[c] = mfma16(A, B, acc[c]);
      }
    }
#pragma unroll
    for (int c = 0; c < 4; ++c){
      int col = 64*w + 16*c + li;
      float bias = fc2b[col];
#pragma unroll
      for (int j = 0; j < 4; ++j)
        x3_s[(4*lg + j)*264 + col] = (_Float16)fmaxf(acc[c][j] + bias, 0.f);
    }
  }
  __syncthreads();
  {
    const int r0 = (b >> 6)*16, t = b & 63;
    f32x4 acc[12];
#pragma unroll
    for (int cc = 0; cc < 12; ++cc) acc[cc] = 0.f;
    for (int kk = 0; kk < 8; ++kk){
      f16x8 A = *(const f16x8*)(x3_s + li*264 + kk*32 + lg*8);
#pragma unroll
      for (int cc = 0; cc < 12; ++cc){
        int col = (w*12 + cc)*16 + li;
        f16x8 B = *(const f16x8*)(GIHT + (size_t)col*256 + kk*32 + lg*8);
        acc[cc] = mfma16(A, B, acc[cc]);
      }
    }
#pragma unroll
    for (int cc = 0; cc < 12; ++cc){
      int col = (w*12 + cc)*16 + li;
      float bias = gib[col];
#pragma unroll
      for (int j = 0; j < 4; ++j){
        int q = 4*lg + j;
        gi[((size_t)((r0 + q)*64 + t))*768 + col] = acc[cc][j] + bias;
      }
    }
  }
}

// ------------------------------------------------------------------ K3: GRU
// Row-partitioned: 32 blocks x 16 rows, 256 threads, h resident in LDS.
__global__ __launch_bounds__(256) void k3_gru(
    const _Float16* __restrict__ WHH, const float* __restrict__ bhh,
    const float* __restrict__ gi, const float* __restrict__ h0,
    float* __restrict__ hs)
{
  const int rb = blockIdx.x;
  const int row0 = rb * 16;
  const int tid = threadIdx.x;
  const int w = tid >> 6, lg = (tid >> 4) & 3, li = tid & 15;

  extern __shared__ char smem3[];
  _Float16* hf16 = (_Float16*)smem3;
  float* hf32 = (float*)(smem3 + 8448);
  float* gh   = (float*)(smem3 + 8448 + 16640);
  float* bhs  = (float*)(smem3 + 8448 + 16640 + 49664);

  for (int idx = tid; idx < 768; idx += 256) bhs[idx] = bhh[idx];
  for (int idx = tid; idx < 4096; idx += 256){
    int r = idx >> 8, d = idx & 255;
    float v = h0[(size_t)(row0 + r)*256 + d];
    hf32[r*260 + d] = v;
    hf16[r*264 + d] = (_Float16)v;
  }
  __syncthreads();

  const int er = tid >> 4;
  const int d0 = (tid & 15) * 16;

  for (int t = 0; t < 64; ++t){
    const float* gp = gi + ((size_t)(row0 + er)*64 + t)*768 + d0;
    f32x4 gr[4], gz[4], gn[4];
#pragma unroll
    for (int v = 0; v < 4; ++v){
      gr[v] = *(const f32x4*)(gp + v*4);
      gz[v] = *(const f32x4*)(gp + 256 + v*4);
      gn[v] = *(const f32x4*)(gp + 512 + v*4);
    }
    f16x8 a[8];
#pragma unroll
    for (int kk = 0; kk < 8; ++kk)
      a[kk] = *(const f16x8*)(hf16 + li*264 + kk*32 + lg*8);
    f32x4 acc[12];
#pragma unroll
    for (int c = 0; c < 12; ++c) acc[c] = 0.f;
#pragma unroll
    for (int c = 0; c < 12; ++c){
      const _Float16* bp = WHH + (size_t)(w*192 + c*16 + li)*256 + lg*8;
#pragma unroll
      for (int kk = 0; kk < 8; ++kk)
        acc[c] = mfma16(a[kk], *(const f16x8*)(bp + kk*32), acc[c]);
    }
#pragma unroll
    for (int c = 0; c < 12; ++c){
      int col = w*192 + c*16 + li;
#pragma unroll
      for (int j = 0; j < 4; ++j)
        gh[(4*lg + j)*776 + col] = acc[c][j];
    }
    __syncthreads();
    {
      float* hp32 = hf32 + er*260 + d0;
      float* hsp  = hs + ((size_t)(rb*64 + t)*16 + er)*256 + d0;
      f16x8 hv8[2];
#pragma unroll
      for (int v = 0; v < 4; ++v){
        f32x4 xr = *(const f32x4*)(gh + er*776 +       d0 + v*4);
        f32x4 xz = *(const f32x4*)(gh + er*776 + 256 + d0 + v*4);
        f32x4 xn = *(const f32x4*)(gh + er*776 + 512 + d0 + v*4);
        f32x4 hold = *(const f32x4*)(hp32 + v*4);
        f32x4 hout;
#pragma unroll
        for (int e = 0; e < 4; ++e){
          int d = d0 + v*4 + e;
          float rr_ = 1.f/(1.f + expf(-(gr[v][e] + xr[e] + bhs[d])));
          float zz  = 1.f/(1.f + expf(-(gz[v][e] + xz[e] + bhs[256 + d])));
          float nn  = tanhf(gn[v][e] + rr_*(xn[e] + bhs[512 + d]));
          float hv = (1.f - zz)*nn + zz*hold[e];
          hout[e] = hv;
          int sl = v*4 + e;
          hv8[sl >> 3][sl & 7] = (_Float16)hv;
        }
        *(f32x4*)(hp32 + v*4) = hout;
        *(f32x4*)(hsp + v*4)  = hout;
      }
      *(f16x8*)(hf16 + er*264 + d0)     = hv8[0];
      *(f16x8*)(hf16 + er*264 + d0 + 8) = hv8[1];
    }
    __syncthreads();
  }
}

// ------------------------------------------------------------------ K4: q out
__global__ __launch_bounds__(256) void k4_q(
    const _Float16* __restrict__ FC3T, const float* __restrict__ fc3b,
    const float* __restrict__ em, const float* __restrict__ hs, float* __restrict__ qo)
{
  const int tid = threadIdx.x;
  const int w = tid >> 6, lg = (tid >> 4) & 3, li = tid & 15;
  const int rb = blockIdx.x*64 + 16*w;
  f32x4 acc[2];
#pragma unroll
  for (int c = 0; c < 2; ++c) acc[c] = 0.f;
  for (int kk = 0; kk < 8; ++kk){
    const float* ap = hs + (size_t)(rb + li)*256 + kk*32 + lg*8;
    f32x4 v0 = *(const f32x4*)ap, v1 = *(const f32x4*)(ap + 4);
    f16x8 A;
#pragma unroll
    for (int e = 0; e < 4; ++e){ A[e] = (_Float16)v0[e]; A[e+4] = (_Float16)v1[e]; }
#pragma unroll
    for (int c = 0; c < 2; ++c){
      f16x8 B = *(const f16x8*)(FC3T + (size_t)(16*c + li)*256 + kk*32 + lg*8);
      acc[c] = mfma16(A, B, acc[c]);
    }
  }
#pragma unroll
  for (int c = 0; c < 2; ++c){
    int col = 16*c + li;
    float bias = fc3b[col];
#pragma unroll
    for (int j = 0; j < 4; ++j){
      int row = rb + 4*lg + j;
      float am = em[(size_t)(row >> 4)*64 + (row & 15)];
      qo[(size_t)row*32 + col] = (acc[c][j] + bias)*(1.f - am);
    }
  }
}

// --------------------------------------------------------------------- launch
extern "C" void kernel_launch(void* const* d_in, const int* in_sizes, int n_in,
                              void* d_out, int out_size, void* d_ws, size_t ws_size,
                              hipStream_t stream)
{
  // ws layout (bytes) — r3 layout
  constexpr size_t OFF_FC1T   = 0;
  constexpr size_t OFF_MSG1T  = 49152;
  constexpr size_t OFF_AINT   = 98304;
  constexpr size_t OFF_LINT   = 491520;
  constexpr size_t OFF_AOUTT  = 884736;
  constexpr size_t OFF_LOUTT  = 1015808;
  constexpr size_t OFF_GMINT  = 1146880;
  constexpr size_t OFF_GMOUTT = 1540096;
  constexpr size_t OFF_FC2T   = 1671168;
  constexpr size_t OFF_GIHT   = 1933312;
  constexpr size_t OFF_GHHT   = 2326528;
  constexpr size_t OFF_FC3T   = 2719744;
  constexpr size_t OFF_G1T    = 2736128;   // f16 hi+lo pair
  constexpr size_t OFF_GINT   = 2834432;   // pair
  constexpr size_t OFF_WVEFF  = 3620864;   // pair
  constexpr size_t OFF_BEFF   = 3637248;
  constexpr size_t OFF_GATE   = 3637504;   // 131072
  constexpr size_t OFF_X2     = 3768576;   // 33554432
  constexpr size_t OFF_X2M    = 37323008;  // 33554432
  constexpr size_t OFF_GI     = 70877440;  // 100663296
  constexpr size_t NEED       = 171540736;
  if (ws_size < NEED) return;

  char* ws = (char*)d_ws;
  const float* ent = (const float*)d_in[0];
  const float* om  = (const float*)d_in[1];
  const float* em  = (const float*)d_in[2];

  WJobs jb{};
  int nj = 0;
  auto addj = [&](int src_idx, size_t off, int K, int N, int m){
    jb.src[nj] = (const float*)d_in[src_idx]; jb.off[nj] = (unsigned)off;
    jb.K[nj] = K; jb.N[nj] = N; jb.mode[nj] = m; ++nj;
  };
  addj(4,  OFF_FC1T,   96, 256, 0);
  addj(17, OFF_MSG1T,  96, 256, 0);
  addj(6,  OFF_AINT,  256, 768, 0);
  addj(19, OFF_LINT,  256, 768, 0);
  addj(7,  OFF_AOUTT, 256, 256, 0);
  addj(20, OFF_LOUTT, 256, 256, 0);
  addj(22, OFF_GMINT, 256, 768, 0);
  addj(23, OFF_GMOUTT,256, 256, 0);
  addj(9,  OFF_FC2T,  512, 256, 0);
  addj(11, OFF_GIHT,  256, 768, 0);
  addj(12, OFF_GHHT,  256, 768, 0);
  addj(15, OFF_FC3T,  256,  32, 0);
  addj(28, OFF_G1T,    96, 256, 1);
  addj(25, OFF_GINT,  256, 768, 1);
  k0_conv<<<dim3(96, nj), 256, 0, stream>>>(jb, ws);

  // gate-tail precompute: Weff/Wveff/beff
  k0w_gate<<<1, 256, 0, stream>>>(
      (const float*)d_in[26], (const float*)d_in[30],
      (const float*)d_in[27], (const float*)d_in[25],
      (_Float16*)(ws + OFF_WVEFF), (float*)(ws + OFF_BEFF));

  constexpr int SM0 = 78336, SMG = 116480, SM3 = 77824;
  (void)hipFuncSetAttribute(reinterpret_cast<const void*>(&k1_branch<0>),
                            hipFuncAttributeMaxDynamicSharedMemorySize, SM0);
  (void)hipFuncSetAttribute(reinterpret_cast<const void*>(&k1_gate),
                            hipFuncAttributeMaxDynamicSharedMemorySize, SMG);
  (void)hipFuncSetAttribute(reinterpret_cast<const void*>(&k3_gru),
                            hipFuncAttributeMaxDynamicSharedMemorySize, SM3);

  float* qout = (float*)d_out;
  float* hsout = qout + 1048576;
  float* gout = qout + 9437184;

  // merged main+msg branches: 4096 blocks, br = blockIdx.x>>11
  k1_branch<0><<<4096, 256, SM0, stream>>>(ent, om, em,
      (const _Float16*)(ws + OFF_FC1T),  (const float*)d_in[5],
      (const _Float16*)(ws + OFF_AINT),
      (const _Float16*)(ws + OFF_AOUTT), (const float*)d_in[8],
      (float*)(ws + OFF_X2),
      (const _Float16*)(ws + OFF_MSG1T), (const float*)d_in[18],
      (const _Float16*)(ws + OFF_LINT),
      (const _Float16*)(ws + OFF_LOUTT), (const float*)d_in[21],
      (float*)(ws + OFF_X2M));
  k1_gate<<<2048, 512, SMG, stream>>>(ent, om, em,
      (const _Float16*)(ws + OFF_G1T),   (const float*)d_in[29],
      (const _Float16*)(ws + OFF_GINT),
      (const _Float16*)(ws + OFF_WVEFF),
      (const float*)(ws + OFF_BEFF), (const float*)d_in[31],
      gout, (float*)(ws + OFF_GATE));

  k2_global<<<2048, 256, 0, stream>>>(em,
      (const float*)(ws + OFF_X2), (const float*)(ws + OFF_X2M),
      (const float*)(ws + OFF_GATE),
      (const _Float16*)(ws + OFF_GMINT), (const _Float16*)(ws + OFF_GMOUTT), (const float*)d_in[24],
      (const _Float16*)(ws + OFF_FC2T), (const float*)d_in[10],
      (const _Float16*)(ws + OFF_GIHT), (const float*)d_in[13],
      (float*)(ws + OFF_GI));

  k3_gru<<<32, 256, SM3, stream>>>(
      (const _Float16*)(ws + OFF_GHHT), (const float*)d_in[14],
      (const float*)(ws + OFF_GI), (const float*)d_in[3], hsout);

  k4_q<<<512, 256, 0, stream>>>(
      (const _Float16*)(ws + OFF_FC3T), (const float*)d_in[16],
      em, hsout, qout);
}

// Round 10
// 1637.537 us; speedup vs baseline: 1.3028x; 1.1033x over previous
//
#include <hip/hip_runtime.h>

// EntityAttentionRNNMsgAgent — fused MI355X implementation.
// r10 = r9 + k1_branch processes 2 batch items per block with B-fragment
// sharing (each weight fragment feeds 2 MFMAs; per-item L2 weight traffic
// halves). Everything else byte-identical to r9 (1806.7us verified).
// Stages:
//  K0:  transpose all weights to f16 [N][K] (gate branch: hi/lo split pair)
//  K0w: gate-tail collapse: Weff = Wout@Wg2, Wveff (256x8), beff — f32, 1 block
//  K1b2: merged main+msg branch attention, 2 items/block (2048 blocks)
//  K1g: gate branch, algebraically reduced: split-2 f16 + f32 P.v2 -> og/gate
//  K2:  gated_msg, global attention, fc2, gru-input GEMM (gi); reads gate flag
//  K3:  64-step GRU, row-partitioned (32 blocks x 16 rows), h resident in LDS
//  K4:  q = hs @ fc3 + b, masked

#define DEV __device__ __forceinline__

typedef _Float16 f16x8 __attribute__((ext_vector_type(8)));
typedef float    f32x4 __attribute__((ext_vector_type(4)));

DEV f32x4 mfma16(f16x8 a, f16x8 b, f32x4 c){
  return __builtin_amdgcn_mfma_f32_16x16x32_f16(a, b, c, 0, 0, 0);
}

// A/B fragment pair for optional split-precision (MODE=1: value = hi + lo)
template<int MODE> struct AB {
  f16x8 hi, lo;
  DEV void mf(const AB& b, f32x4& c) const {
    if constexpr (MODE){
      c = mfma16(lo, b.hi, c);
      c = mfma16(hi, b.lo, c);
    }
    c = mfma16(hi, b.hi, c);
  }
};

template<int MODE> DEV AB<MODE> ldW(const _Float16* p, int losz){
  AB<MODE> r; r.hi = *(const f16x8*)p;
  if constexpr (MODE) r.lo = *(const f16x8*)(p + losz);
  return r;
}
template<int MODE> DEV AB<MODE> ldL(const _Float16* ph, const _Float16* pl){
  AB<MODE> r; r.hi = *(const f16x8*)ph;
  if constexpr (MODE) r.lo = *(const f16x8*)pl;
  return r;
}
template<int MODE> DEV AB<MODE> ldF(const float* p){
  AB<MODE> r;
  f32x4 v0 = *(const f32x4*)p, v1 = *(const f32x4*)(p + 4);
#pragma unroll
  for (int i = 0; i < 4; ++i){
    float a = v0[i], b = v1[i];
    _Float16 ah = (_Float16)a, bh = (_Float16)b;
    r.hi[i] = ah; r.hi[i+4] = bh;
    if constexpr (MODE){
      r.lo[i]   = (_Float16)(a - (float)ah);
      r.lo[i+4] = (_Float16)(b - (float)bh);
    }
  }
  return r;
}
template<int MODE> DEV void stL(_Float16* ph, _Float16* pl, int idx, float v){
  _Float16 h = (_Float16)v;
  ph[idx] = h;
  if constexpr (MODE) pl[idx] = (_Float16)(v - (float)h);
}

// ---------------------------------------------------------------- K0: weights
struct WJobs {
  const float* src[15];
  unsigned off[15];
  int K[15], N[15], mode[15];
};

__global__ __launch_bounds__(256) void k0_conv(WJobs jb, char* ws){
  const int job = blockIdx.y;
  const int K = jb.K[job], N = jb.N[job];
  const int total = K * N;
  _Float16* dh = (_Float16*)(ws + jb.off[job]);
  const float* src = jb.src[job];
  const int m = jb.mode[job];
  for (int idx = blockIdx.x*256 + threadIdx.x; idx < total; idx += gridDim.x*256){
    int n = idx / K, k = idx - n*K;
    float v = src[(size_t)k*N + n];
    _Float16 h = (_Float16)v;
    dh[idx] = h;
    if (m) dh[total + idx] = (_Float16)(v - (float)h);
  }
}

// ------------------------------------------------- K0w: gate-tail precompute
__global__ __launch_bounds__(256) void k0w_gate(
    const float* __restrict__ Wout, const float* __restrict__ Wg2,
    const float* __restrict__ bo,   const float* __restrict__ Win,
    _Float16* __restrict__ wveff, float* __restrict__ beff)
{
  __shared__ float weff_s[256*2];
  const int tid = threadIdx.x;
  {
    float a0 = 0.f, a1 = 0.f;
    const float* wr = Wout + (size_t)tid*256;
    for (int f = 0; f < 256; ++f){ float x = wr[f]; a0 += x*Wg2[2*f]; a1 += x*Wg2[2*f+1]; }
    weff_s[tid*2] = a0; weff_s[tid*2+1] = a1;
  }
  if (tid < 2){
    float s = 0.f;
    for (int f = 0; f < 256; ++f) s += bo[f]*Wg2[2*f + tid];
    beff[tid] = s;
  }
  __syncthreads();
  {
    const int j = tid;
    for (int n = 0; n < 16; ++n){
      float v = 0.f;
      if (n < 8){
        int h = n >> 1, c = n & 1;
        const float* wr = Win + (size_t)j*768 + 512 + h*64;
        const float* we = weff_s + (h*64)*2 + c;
        for (int d = 0; d < 64; ++d) v += wr[d]*we[2*d];
      }
      _Float16 hi = (_Float16)v;
      wveff[n*256 + j] = hi;
      wveff[16*256 + n*256 + j] = (_Float16)(v - (float)hi);
    }
  }
}

// ------------------------------------------- K1b2: branch attention, 2 items
// 2048 blocks; br = blockIdx.x>>10 selects {main,msg}; pair p = blockIdx.x&1023
// handles items b0=2p, b1=2p+1. 256 threads = 4 waves. Weight fragments are
// loaded once and applied to both items (B-traffic per item halves).
__global__ __launch_bounds__(256) void k1_branch2(
    const float* __restrict__ ent, const float* __restrict__ om, const float* __restrict__ em,
    const _Float16* __restrict__ W1a, const float* __restrict__ b1a,
    const _Float16* __restrict__ WINa,
    const _Float16* __restrict__ WOUTa, const float* __restrict__ boa,
    float* __restrict__ x2outa,
    const _Float16* __restrict__ W1b, const float* __restrict__ b1b,
    const _Float16* __restrict__ WINb,
    const _Float16* __restrict__ WOUTb, const float* __restrict__ bob,
    float* __restrict__ x2outb)
{
  const int br = blockIdx.x >> 10;
  const int p  = blockIdx.x & 1023;
  const int bb2[2] = { 2*p, 2*p + 1 };
  const _Float16* W1   = br ? W1b   : W1a;
  const float*    b1   = br ? b1b   : b1a;
  const _Float16* WIN  = br ? WINb  : WINa;
  const _Float16* WOUT = br ? WOUTb : WOUTa;
  const float*    bo   = br ? bob   : boa;
  float*          x2out= br ? x2outb: x2outa;

  const int tid = threadIdx.x;
  const int w = tid >> 6, lg = (tid >> 4) & 3, li = tid & 15;

  extern __shared__ char smem[];
  _Float16* x1  = (_Float16*)smem;               // [2][64*264]  67584 B
  _Float16* Ks  = (_Float16*)(smem + 67584);     // [2][64*72]   18432 B
  _Float16* Vs  = (_Float16*)(smem + 86016);     // [2][64*72]T  18432 B
  _Float16* Qs  = (_Float16*)(smem + 104448);    // [2][16*72]    4608 B
  float*    lgs = (float*)(smem + 109056);       // [2][16*72]    9216 B
  _Float16* Ps  = (_Float16*)(smem + 118272);    // [2][16*72]    4608 B
  float*    outp= (float*)(smem + 122880);       // [2][16*264]  33792 B
  // total 156672 B

  // ---- phase 1: x1 = relu(ent @ W1 + b1), per item (W1 traffic is minor)
  for (int it = 0; it < 2; ++it){
    const int b = bb2[it];
    _Float16* x1p = x1 + it*16896;
    f32x4 acc[4][4];
#pragma unroll
    for (int r = 0; r < 4; ++r)
#pragma unroll
      for (int c = 0; c < 4; ++c) acc[r][c] = 0.f;
#pragma unroll
    for (int kk = 0; kk < 3; ++kk){
      AB<0> a[4];
#pragma unroll
      for (int r = 0; r < 4; ++r)
        a[r] = ldF<0>(ent + ((size_t)b*64 + 16*r + li)*96 + kk*32 + lg*8);
#pragma unroll
      for (int c = 0; c < 4; ++c){
        f16x8 B = *(const f16x8*)(W1 + (size_t)(64*w + 16*c + li)*96 + kk*32 + lg*8);
#pragma unroll
        for (int r = 0; r < 4; ++r) acc[r][c] = mfma16(a[r].hi, B, acc[r][c]);
      }
    }
#pragma unroll
    for (int c = 0; c < 4; ++c){
      int col = 64*w + 16*c + li;
      float bias = b1[col];
#pragma unroll
      for (int r = 0; r < 4; ++r)
#pragma unroll
        for (int j = 0; j < 4; ++j){
          float v = fmaxf(acc[r][c][j] + bias, 0.f);
          x1p[(16*r + 4*lg + j)*264 + col] = (_Float16)v;
        }
    }
  }
  __syncthreads();

  // ---- phase 2: per-head attention (B shared across items)
  for (int h = 0; h < 4; ++h){
    { // K_h: wave w -> keys 16w..16w+15, 4 dim-tiles, both items
      f32x4 acc[2][4];
#pragma unroll
      for (int it = 0; it < 2; ++it)
#pragma unroll
        for (int c = 0; c < 4; ++c) acc[it][c] = 0.f;
      for (int kk = 0; kk < 8; ++kk){
        int ao = (16*w + li)*264 + kk*32 + lg*8;
        f16x8 A0 = *(const f16x8*)(x1 + ao);
        f16x8 A1 = *(const f16x8*)(x1 + 16896 + ao);
#pragma unroll
        for (int c = 0; c < 4; ++c){
          f16x8 B = *(const f16x8*)(WIN + (size_t)(256 + 64*h + 16*c + li)*256 + kk*32 + lg*8);
          acc[0][c] = mfma16(A0, B, acc[0][c]);
          acc[1][c] = mfma16(A1, B, acc[1][c]);
        }
      }
#pragma unroll
      for (int it = 0; it < 2; ++it)
#pragma unroll
        for (int c = 0; c < 4; ++c)
#pragma unroll
          for (int j = 0; j < 4; ++j)
            Ks[it*4608 + (16*w + 4*lg + j)*72 + 16*c + li] = (_Float16)acc[it][c][j];
    }
    { // V_h (stored transposed), both items
      f32x4 acc[2][4];
#pragma unroll
      for (int it = 0; it < 2; ++it)
#pragma unroll
        for (int c = 0; c < 4; ++c) acc[it][c] = 0.f;
      for (int kk = 0; kk < 8; ++kk){
        int ao = (16*w + li)*264 + kk*32 + lg*8;
        f16x8 A0 = *(const f16x8*)(x1 + ao);
        f16x8 A1 = *(const f16x8*)(x1 + 16896 + ao);
#pragma unroll
        for (int c = 0; c < 4; ++c){
          f16x8 B = *(const f16x8*)(WIN + (size_t)(512 + 64*h + 16*c + li)*256 + kk*32 + lg*8);
          acc[0][c] = mfma16(A0, B, acc[0][c]);
          acc[1][c] = mfma16(A1, B, acc[1][c]);
        }
      }
#pragma unroll
      for (int it = 0; it < 2; ++it)
#pragma unroll
        for (int c = 0; c < 4; ++c)
#pragma unroll
          for (int j = 0; j < 4; ++j)
            Vs[it*4608 + (16*c + li)*72 + 16*w + 4*lg + j] = (_Float16)acc[it][c][j];
    }
    { // Q_h: rows 0..15, wave w -> dim tile w, both items
      f32x4 acc[2];
      acc[0] = 0.f; acc[1] = 0.f;
      for (int kk = 0; kk < 8; ++kk){
        int ao = li*264 + kk*32 + lg*8;
        f16x8 A0 = *(const f16x8*)(x1 + ao);
        f16x8 A1 = *(const f16x8*)(x1 + 16896 + ao);
        f16x8 B = *(const f16x8*)(WIN + (size_t)(64*h + 16*w + li)*256 + kk*32 + lg*8);
        acc[0] = mfma16(A0, B, acc[0]);
        acc[1] = mfma16(A1, B, acc[1]);
      }
#pragma unroll
      for (int it = 0; it < 2; ++it)
#pragma unroll
        for (int j = 0; j < 4; ++j)
          Qs[it*1152 + (4*lg + j)*72 + 16*w + li] = (_Float16)acc[it][j];
    }
    __syncthreads();
    { // logits = Q K^T / 8, masked (LDS-only; loop items)
#pragma unroll
      for (int it = 0; it < 2; ++it){
        const int b = bb2[it];
        f32x4 acc = 0.f;
#pragma unroll
        for (int kk = 0; kk < 2; ++kk){
          f16x8 A = *(const f16x8*)(Qs + it*1152 + li*72 + kk*32 + lg*8);
          f16x8 B = *(const f16x8*)(Ks + it*4608 + (16*w + li)*72 + kk*32 + lg*8);
          acc = mfma16(A, B, acc);
        }
#pragma unroll
        for (int j = 0; j < 4; ++j){
          int q = 4*lg + j, key = 16*w + li;
          float v = acc[j] * 0.125f;
          float m = om[((size_t)b*64 + q)*64 + key];
          if (m > 0.f) v = -1e9f;
          lgs[it*1152 + q*72 + key] = v;
        }
      }
    }
    __syncthreads();
    { // softmax over 64 keys, 16 threads per query; loop items
      int q = tid >> 4, i16 = tid & 15;
#pragma unroll
      for (int it = 0; it < 2; ++it){
        const int b = bb2[it];
        float pv[4], mx = -3e38f;
#pragma unroll
        for (int u = 0; u < 4; ++u){ pv[u] = lgs[it*1152 + q*72 + i16 + 16*u]; mx = fmaxf(mx, pv[u]); }
#pragma unroll
        for (int d = 1; d < 16; d <<= 1) mx = fmaxf(mx, __shfl_xor(mx, d, 16));
        float s = 0.f;
#pragma unroll
        for (int u = 0; u < 4; ++u){ pv[u] = expf(pv[u] - mx); s += pv[u]; }
#pragma unroll
        for (int d = 1; d < 16; d <<= 1) s += __shfl_xor(s, d, 16);
#pragma unroll
        for (int u = 0; u < 4; ++u){
          int key = i16 + 16*u;
          float m = om[((size_t)b*64 + q)*64 + key];
          Ps[it*1152 + q*72 + key] = (_Float16)((pv[u]/s)*(1.f - m));
        }
      }
    }
    __syncthreads();
    { // out_h = P @ V_h (LDS-only; loop items)
#pragma unroll
      for (int it = 0; it < 2; ++it){
        f32x4 acc = 0.f;
#pragma unroll
        for (int kk = 0; kk < 2; ++kk){
          f16x8 A = *(const f16x8*)(Ps + it*1152 + li*72 + kk*32 + lg*8);
          f16x8 B = *(const f16x8*)(Vs + it*4608 + (16*w + li)*72 + kk*32 + lg*8);
          acc = mfma16(A, B, acc);
        }
#pragma unroll
        for (int j = 0; j < 4; ++j)
          outp[it*4224 + (4*lg + j)*264 + 64*h + 16*w + li] = acc[j];
      }
    }
    __syncthreads();
  }

  // ---- phase 3: out-proj + bias + post-mask (B shared across items)
  {
    f32x4 acc[2][4];
#pragma unroll
    for (int it = 0; it < 2; ++it)
#pragma unroll
      for (int c = 0; c < 4; ++c) acc[it][c] = 0.f;
    for (int kk = 0; kk < 8; ++kk){
      AB<0> a0 = ldF<0>(outp + li*264 + kk*32 + lg*8);
      AB<0> a1 = ldF<0>(outp + 4224 + li*264 + kk*32 + lg*8);
#pragma unroll
      for (int c = 0; c < 4; ++c){
        f16x8 B = *(const f16x8*)(WOUT + (size_t)(64*w + 16*c + li)*256 + kk*32 + lg*8);
        acc[0][c] = mfma16(a0.hi, B, acc[0][c]);
        acc[1][c] = mfma16(a1.hi, B, acc[1][c]);
      }
    }
#pragma unroll
    for (int it = 0; it < 2; ++it){
      const int b = bb2[it];
#pragma unroll
      for (int c = 0; c < 4; ++c){
        int col = 64*w + 16*c + li;
        float bias = bo[col];
#pragma unroll
        for (int j = 0; j < 4; ++j){
          int q = 4*lg + j;
          float v = (acc[it][c][j] + bias) * (1.f - em[(size_t)b*64 + q]);
          x2out[((size_t)b*16 + q)*256 + col] = v;
        }
      }
    }
  }
}

// --------------------------------------------- K1g: reduced gate branch
// 512 threads = 8 waves, one block per batch item.
__global__ __launch_bounds__(512) void k1_gate(
    const float* __restrict__ ent, const float* __restrict__ om, const float* __restrict__ em,
    const _Float16* __restrict__ W1, const float* __restrict__ b1,
    const _Float16* __restrict__ WIN,
    const _Float16* __restrict__ WVEFF,
    const float* __restrict__ beff, const float* __restrict__ gb2,
    float* __restrict__ og, float* __restrict__ gate)
{
  constexpr int W1SZ = 96*256, WINSZ = 256*768, WVSZ = 16*256;
  const int b = blockIdx.x;
  const int tid = threadIdx.x;
  const int w = tid >> 6, lg = (tid >> 4) & 3, li = tid & 15;

  extern __shared__ char smem[];
  char* sp = smem;
  _Float16* x1h = (_Float16*)sp; sp += 64*264*2;
  _Float16* x1l = (_Float16*)sp; sp += 64*264*2;
  _Float16* Kh  = (_Float16*)sp; sp += 64*72*2;
  _Float16* Kl  = (_Float16*)sp; sp += 64*72*2;
  _Float16* Qh  = (_Float16*)sp; sp += 16*264*2;
  _Float16* Ql  = (_Float16*)sp; sp += 16*264*2;
  float*    lgs = (float*)sp;    sp += 16*72*4;
  float*    Ps  = (float*)sp;    sp += 16*66*4;
  float*    v2s = (float*)sp;    sp += 64*18*4;
  float*  ogacc = (float*)sp;    sp += 32*4;

  // ---- phase 1: x1 = relu(ent @ W1 + b1); wave w -> m-tile w>>1, 8 n-tiles
  {
    const int mt = w >> 1;
    f32x4 acc[8];
#pragma unroll
    for (int c = 0; c < 8; ++c) acc[c] = 0.f;
#pragma unroll
    for (int kk = 0; kk < 3; ++kk){
      AB<1> a = ldF<1>(ent + ((size_t)b*64 + mt*16 + li)*96 + kk*32 + lg*8);
#pragma unroll
      for (int c = 0; c < 8; ++c){
        int nt = (w & 1)*8 + c;
        AB<1> bb = ldW<1>(W1 + (size_t)(nt*16 + li)*96 + kk*32 + lg*8, W1SZ);
        a.mf(bb, acc[c]);
      }
    }
#pragma unroll
    for (int c = 0; c < 8; ++c){
      int col = ((w & 1)*8 + c)*16 + li;
      float bias = b1[col];
#pragma unroll
      for (int j = 0; j < 4; ++j){
        float v = fmaxf(acc[c][j] + bias, 0.f);
        stL<1>(x1h, x1l, (mt*16 + 4*lg + j)*264 + col, v);
      }
    }
  }
  if (tid < 32) ogacc[tid] = 0.f;
  __syncthreads();

  // ---- phase 2: Qfull = x1[0:16] @ Wq (16 n-tiles), v2 = x1 @ Wveff (4 m-tiles)
  {
#pragma unroll
    for (int s = 0; s < 2; ++s){
      int nt = w + s*8;
      f32x4 acc = 0.f;
      for (int kk = 0; kk < 8; ++kk){
        int ao = li*264 + kk*32 + lg*8;
        AB<1> a = ldL<1>(x1h + ao, x1l + ao);
        AB<1> bb = ldW<1>(WIN + (size_t)(nt*16 + li)*256 + kk*32 + lg*8, WINSZ);
        a.mf(bb, acc);
      }
#pragma unroll
      for (int j = 0; j < 4; ++j)
        stL<1>(Qh, Ql, (4*lg + j)*264 + nt*16 + li, acc[j]);
    }
    if (w < 4){   // v2 m-tile w
      f32x4 acc = 0.f;
      for (int kk = 0; kk < 8; ++kk){
        int ao = (w*16 + li)*264 + kk*32 + lg*8;
        AB<1> a = ldL<1>(x1h + ao, x1l + ao);
        AB<1> bb = ldW<1>(WVEFF + (size_t)li*256 + kk*32 + lg*8, WVSZ);
        a.mf(bb, acc);
      }
#pragma unroll
      for (int j = 0; j < 4; ++j)
        v2s[(w*16 + 4*lg + j)*18 + li] = acc[j];
    }
  }
  __syncthreads();

  // ---- head loop
  for (int h = 0; h < 4; ++h){
    { // K_h: wave w -> m-tile w>>1, 2 n-tiles
      const int mt = w >> 1;
      f32x4 acc[2];
      acc[0] = 0.f; acc[1] = 0.f;
      for (int kk = 0; kk < 8; ++kk){
        int ao = (mt*16 + li)*264 + kk*32 + lg*8;
        AB<1> a = ldL<1>(x1h + ao, x1l + ao);
#pragma unroll
        for (int c = 0; c < 2; ++c){
          int nt = (w & 1)*2 + c;
          AB<1> bb = ldW<1>(WIN + (size_t)(256 + h*64 + nt*16 + li)*256 + kk*32 + lg*8, WINSZ);
          a.mf(bb, acc[c]);
        }
      }
#pragma unroll
      for (int c = 0; c < 2; ++c){
        int colb = ((w & 1)*2 + c)*16 + li;
#pragma unroll
        for (int j = 0; j < 4; ++j)
          stL<1>(Kh, Kl, (mt*16 + 4*lg + j)*72 + colb, acc[c][j]);
      }
    }
    __syncthreads();
    if (w < 4){ // logits: keys 16w..16w+15
      f32x4 acc = 0.f;
#pragma unroll
      for (int kk = 0; kk < 2; ++kk){
        int ao = li*264 + h*64 + kk*32 + lg*8;
        AB<1> a = ldL<1>(Qh + ao, Ql + ao);
        int bo_ = (16*w + li)*72 + kk*32 + lg*8;
        AB<1> bb = ldL<1>(Kh + bo_, Kl + bo_);
        a.mf(bb, acc);
      }
#pragma unroll
      for (int j = 0; j < 4; ++j){
        int q = 4*lg + j, key = 16*w + li;
        float v = acc[j] * 0.125f;
        float m = om[((size_t)b*64 + q)*64 + key];
        if (m > 0.f) v = -1e9f;
        lgs[q*72 + key] = v;
      }
    }
    __syncthreads();
    if (tid < 256){ // softmax
      int q = tid >> 4, i16 = tid & 15;
      float pv[4], mx = -3e38f;
#pragma unroll
      for (int u = 0; u < 4; ++u){ pv[u] = lgs[q*72 + i16 + 16*u]; mx = fmaxf(mx, pv[u]); }
#pragma unroll
      for (int d = 1; d < 16; d <<= 1) mx = fmaxf(mx, __shfl_xor(mx, d, 16));
      float s = 0.f;
#pragma unroll
      for (int u = 0; u < 4; ++u){ pv[u] = expf(pv[u] - mx); s += pv[u]; }
#pragma unroll
      for (int d = 1; d < 16; d <<= 1) s += __shfl_xor(s, d, 16);
#pragma unroll
      for (int u = 0; u < 4; ++u){
        int key = i16 + 16*u;
        float m = om[((size_t)b*64 + q)*64 + key];
        Ps[q*66 + key] = (pv[u]/s)*(1.f - m);
      }
    }
    __syncthreads();
    if (tid < 256){ // og += P_h . v2_h  (f32)
      int q = tid >> 4, l16 = tid & 15;
      float a0 = 0.f, a1 = 0.f;
#pragma unroll
      for (int u = 0; u < 4; ++u){
        int k = l16 + 16*u;
        float p = Ps[q*66 + k];
        a0 += p * v2s[k*18 + h*2];
        a1 += p * v2s[k*18 + h*2 + 1];
      }
#pragma unroll
      for (int d = 1; d < 16; d <<= 1){ a0 += __shfl_xor(a0, d, 16); a1 += __shfl_xor(a1, d, 16); }
      if (l16 == 0){ ogacc[q*2] += a0; ogacc[q*2 + 1] += a1; }
    }
    __syncthreads();
  }
  // epilogue: og + gate
  if (tid < 16){
    int q = tid;
    float am = em[(size_t)b*64 + q];
    float g0 = (1.f - am)*(ogacc[2*q]     + beff[0]) + gb2[0];
    float g1 = (1.f - am)*(ogacc[2*q + 1] + beff[1]) + gb2[1];
    og[((size_t)b*16 + q)*2]     = g0;
    og[((size_t)b*16 + q)*2 + 1] = g1;
    gate[(size_t)b*16 + q] = (g1 > g0) ? 1.f : 0.f;
  }
}

// ----------------------------------------- K2: gate, global attention, fc2, gi
__global__ __launch_bounds__(256) void k2_global(
    const float* __restrict__ em,
    const float* __restrict__ x2, const float* __restrict__ x2m,
    const float* __restrict__ gate,
    const _Float16* __restrict__ GMIN, const _Float16* __restrict__ GMOUT, const float* __restrict__ gob,
    const _Float16* __restrict__ FC2T, const float* __restrict__ fc2b,
    const _Float16* __restrict__ GIHT, const float* __restrict__ gib,
    float* __restrict__ gi)
{
  const int b = blockIdx.x;
  const int tid = threadIdx.x;
  const int w = tid >> 6, lg = (tid >> 4) & 3, li = tid & 15;

  __shared__ float gate_s[16];
  __shared__ __align__(16) _Float16 gm_s[16*264];
  __shared__ __align__(16) _Float16 Q2[16*72];
  __shared__ __align__(16) _Float16 K2s[16*72];
  __shared__ __align__(16) _Float16 Vt2[64*40];
  __shared__ float lg2[16*24];
  __shared__ __align__(16) _Float16 P2[16*40];
  __shared__ __align__(16) float outp[16*264];
  __shared__ __align__(16) _Float16 cat_s[16*520];
  __shared__ __align__(16) _Float16 x3_s[16*264];

  if (tid < 16) gate_s[tid] = gate[(size_t)b*16 + tid];
  __syncthreads();
  for (int idx = tid; idx < 4096; idx += 256){
    int q = idx >> 8, d = idx & 255;
    gm_s[q*264 + d]  = (_Float16)(x2m[((size_t)b*16 + q)*256 + d] * gate_s[q]);
    cat_s[q*520 + d] = (_Float16)(x2[((size_t)b*16 + q)*256 + d]);
  }
  for (int idx = tid; idx < 64*40; idx += 256) Vt2[idx] = (_Float16)0.f;
  for (int idx = tid; idx < 16*40; idx += 256) P2[idx] = (_Float16)0.f;
  __syncthreads();
  for (int h = 0; h < 4; ++h){
    {
      f32x4 aq = 0.f, ak = 0.f, av = 0.f;
      for (int kk = 0; kk < 8; ++kk){
        f16x8 A  = *(const f16x8*)(gm_s + li*264 + kk*32 + lg*8);
        f16x8 Bq = *(const f16x8*)(GMIN + (size_t)(      64*h + 16*w + li)*256 + kk*32 + lg*8);
        f16x8 Bk = *(const f16x8*)(GMIN + (size_t)(256 + 64*h + 16*w + li)*256 + kk*32 + lg*8);
        f16x8 Bv = *(const f16x8*)(GMIN + (size_t)(512 + 64*h + 16*w + li)*256 + kk*32 + lg*8);
        aq = mfma16(A, Bq, aq); ak = mfma16(A, Bk, ak); av = mfma16(A, Bv, av);
      }
#pragma unroll
      for (int j = 0; j < 4; ++j){
        int rw = 4*lg + j, dim = 16*w + li;
        Q2[rw*72 + dim]  = (_Float16)aq[j];
        K2s[rw*72 + dim] = (_Float16)ak[j];
        Vt2[dim*40 + rw] = (_Float16)av[j];
      }
    }
    __syncthreads();
    if (w == 0){
      f32x4 acc = 0.f;
#pragma unroll
      for (int kk = 0; kk < 2; ++kk){
        f16x8 A = *(const f16x8*)(Q2  + li*72 + kk*32 + lg*8);
        f16x8 B = *(const f16x8*)(K2s + li*72 + kk*32 + lg*8);
        acc = mfma16(A, B, acc);
      }
      float amk = em[(size_t)b*64 + li];
#pragma unroll
      for (int j = 0; j < 4; ++j){
        int q = 4*lg + j;
        float amq = em[(size_t)b*64 + q];
        float m = 1.f - (1.f - amq)*(1.f - amk);
        float v = acc[j]*0.125f;
        if (m > 0.f) v = -1e9f;
        lg2[q*24 + li] = v;
      }
    }
    __syncthreads();
    {
      int q = tid >> 4, key = tid & 15;
      float v = lg2[q*24 + key];
      float mx = v;
#pragma unroll
      for (int d = 1; d < 16; d <<= 1) mx = fmaxf(mx, __shfl_xor(mx, d, 16));
      float pe = expf(v - mx);
      float s = pe;
#pragma unroll
      for (int d = 1; d < 16; d <<= 1) s += __shfl_xor(s, d, 16);
      float amq = em[(size_t)b*64 + q], amk = em[(size_t)b*64 + key];
      float m = 1.f - (1.f - amq)*(1.f - amk);
      P2[q*40 + key] = (_Float16)((pe/s)*(1.f - m));
    }
    __syncthreads();
    {
      f32x4 acc = 0.f;
      f16x8 A = *(const f16x8*)(P2 + li*40 + lg*8);
      f16x8 B = *(const f16x8*)(Vt2 + (16*w + li)*40 + lg*8);
      acc = mfma16(A, B, acc);
#pragma unroll
      for (int j = 0; j < 4; ++j)
        outp[(4*lg + j)*264 + 64*h + 16*w + li] = acc[j];
    }
    __syncthreads();
  }
  {
    f32x4 acc[4];
#pragma unroll
    for (int c = 0; c < 4; ++c) acc[c] = 0.f;
    for (int kk = 0; kk < 8; ++kk){
      const float* ap = outp + li*264 + kk*32 + lg*8;
      f32x4 v0 = *(const f32x4*)ap, v1 = *(const f32x4*)(ap + 4);
      f16x8 A;
#pragma unroll
      for (int e = 0; e < 4; ++e){ A[e] = (_Float16)v0[e]; A[e+4] = (_Float16)v1[e]; }
#pragma unroll
      for (int c = 0; c < 4; ++c){
        f16x8 B = *(const f16x8*)(GMOUT + (size_t)(64*w + 16*c + li)*256 + kk*32 + lg*8);
        acc[c] = mfma16(A, B, acc[c]);
      }
    }
#pragma unroll
    for (int c = 0; c < 4; ++c){
      int col = 64*w + 16*c + li;
      float bias = gob[col];
#pragma unroll
      for (int j = 0; j < 4; ++j){
        int q = 4*lg + j;
        float v = (acc[c][j] + bias)*(1.f - em[(size_t)b*64 + q]);
        cat_s[q*520 + 256 + col] = (_Float16)v;
      }
    }
  }
  __syncthreads();
  {
    f32x4 acc[4];
#pragma unroll
    for (int c = 0; c < 4; ++c) acc[c] = 0.f;
    for (int kk = 0; kk < 16; ++kk){
      f16x8 A = *(const f16x8*)(cat_s + li*520 + kk*32 + lg*8);
#pragma unroll
      for (int c = 0; c < 4; ++c){
        f16x8 B = *(const f16x8*)(FC2T + (size_t)(64*w + 16*c + li)*512 + kk*32 + lg*8);
        acc[c] = mfma16(A, B, acc[c]);
      }
    }
#pragma unroll
    for (int c = 0; c < 4; ++c){
      int col = 64*w + 16*c + li;
      float bias = fc2b[col];
#pragma unroll
      for (int j = 0; j < 4; ++j)
        x3_s[(4*lg + j)*264 + col] = (_Float16)fmaxf(acc[c][j] + bias, 0.f);
    }
  }
  __syncthreads();
  {
    const int r0 = (b >> 6)*16, t = b & 63;
    f32x4 acc[12];
#pragma unroll
    for (int cc = 0; cc < 12; ++cc) acc[cc] = 0.f;
    for (int kk = 0; kk < 8; ++kk){
      f16x8 A = *(const f16x8*)(x3_s + li*264 + kk*32 + lg*8);
#pragma unroll
      for (int cc = 0; cc < 12; ++cc){
        int col = (w*12 + cc)*16 + li;
        f16x8 B = *(const f16x8*)(GIHT + (size_t)col*256 + kk*32 + lg*8);
        acc[cc] = mfma16(A, B, acc[cc]);
      }
    }
#pragma unroll
    for (int cc = 0; cc < 12; ++cc){
      int col = (w*12 + cc)*16 + li;
      float bias = gib[col];
#pragma unroll
      for (int j = 0; j < 4; ++j){
        int q = 4*lg + j;
        gi[((size_t)((r0 + q)*64 + t))*768 + col] = acc[cc][j] + bias;
      }
    }
  }
}

// ------------------------------------------------------------------ K3: GRU
__global__ __launch_bounds__(256) void k3_gru(
    const _Float16* __restrict__ WHH, const float* __restrict__ bhh,
    const float* __restrict__ gi, const float* __restrict__ h0,
    float* __restrict__ hs)
{
  const int rb = blockIdx.x;
  const int row0 = rb * 16;
  const int tid = threadIdx.x;
  const int w = tid >> 6, lg = (tid >> 4) & 3, li = tid & 15;

  extern __shared__ char smem3[];
  _Float16* hf16 = (_Float16*)smem3;
  float* hf32 = (float*)(smem3 + 8448);
  float* gh   = (float*)(smem3 + 8448 + 16640);
  float* bhs  = (float*)(smem3 + 8448 + 16640 + 49664);

  for (int idx = tid; idx < 768; idx += 256) bhs[idx] = bhh[idx];
  for (int idx = tid; idx < 4096; idx += 256){
    int r = idx >> 8, d = idx & 255;
    float v = h0[(size_t)(row0 + r)*256 + d];
    hf32[r*260 + d] = v;
    hf16[r*264 + d] = (_Float16)v;
  }
  __syncthreads();

  const int er = tid >> 4;
  const int d0 = (tid & 15) * 16;

  for (int t = 0; t < 64; ++t){
    const float* gp = gi + ((size_t)(row0 + er)*64 + t)*768 + d0;
    f32x4 gr[4], gz[4], gn[4];
#pragma unroll
    for (int v = 0; v < 4; ++v){
      gr[v] = *(const f32x4*)(gp + v*4);
      gz[v] = *(const f32x4*)(gp + 256 + v*4);
      gn[v] = *(const f32x4*)(gp + 512 + v*4);
    }
    f16x8 a[8];
#pragma unroll
    for (int kk = 0; kk < 8; ++kk)
      a[kk] = *(const f16x8*)(hf16 + li*264 + kk*32 + lg*8);
    f32x4 acc[12];
#pragma unroll
    for (int c = 0; c < 12; ++c) acc[c] = 0.f;
#pragma unroll
    for (int c = 0; c < 12; ++c){
      const _Float16* bp = WHH + (size_t)(w*192 + c*16 + li)*256 + lg*8;
#pragma unroll
      for (int kk = 0; kk < 8; ++kk)
        acc[c] = mfma16(a[kk], *(const f16x8*)(bp + kk*32), acc[c]);
    }
#pragma unroll
    for (int c = 0; c < 12; ++c){
      int col = w*192 + c*16 + li;
#pragma unroll
      for (int j = 0; j < 4; ++j)
        gh[(4*lg + j)*776 + col] = acc[c][j];
    }
    __syncthreads();
    {
      float* hp32 = hf32 + er*260 + d0;
      float* hsp  = hs + ((size_t)(rb*64 + t)*16 + er)*256 + d0;
      f16x8 hv8[2];
#pragma unroll
      for (int v = 0; v < 4; ++v){
        f32x4 xr = *(const f32x4*)(gh + er*776 +       d0 + v*4);
        f32x4 xz = *(const f32x4*)(gh + er*776 + 256 + d0 + v*4);
        f32x4 xn = *(const f32x4*)(gh + er*776 + 512 + d0 + v*4);
        f32x4 hold = *(const f32x4*)(hp32 + v*4);
        f32x4 hout;
#pragma unroll
        for (int e = 0; e < 4; ++e){
          int d = d0 + v*4 + e;
          float rr_ = 1.f/(1.f + expf(-(gr[v][e] + xr[e] + bhs[d])));
          float zz  = 1.f/(1.f + expf(-(gz[v][e] + xz[e] + bhs[256 + d])));
          float nn  = tanhf(gn[v][e] + rr_*(xn[e] + bhs[512 + d]));
          float hv = (1.f - zz)*nn + zz*hold[e];
          hout[e] = hv;
          int sl = v*4 + e;
          hv8[sl >> 3][sl & 7] = (_Float16)hv;
        }
        *(f32x4*)(hp32 + v*4) = hout;
        *(f32x4*)(hsp + v*4)  = hout;
      }
      *(f16x8*)(hf16 + er*264 + d0)     = hv8[0];
      *(f16x8*)(hf16 + er*264 + d0 + 8) = hv8[1];
    }
    __syncthreads();
  }
}

// ------------------------------------------------------------------ K4: q out
__global__ __launch_bounds__(256) void k4_q(
    const _Float16* __restrict__ FC3T, const float* __restrict__ fc3b,
    const float* __restrict__ em, const float* __restrict__ hs, float* __restrict__ qo)
{
  const int tid = threadIdx.x;
  const int w = tid >> 6, lg = (tid >> 4) & 3, li = tid & 15;
  const int rb = blockIdx.x*64 + 16*w;
  f32x4 acc[2];
#pragma unroll
  for (int c = 0; c < 2; ++c) acc[c] = 0.f;
  for (int kk = 0; kk < 8; ++kk){
    const float* ap = hs + (size_t)(rb + li)*256 + kk*32 + lg*8;
    f32x4 v0 = *(const f32x4*)ap, v1 = *(const f32x4*)(ap + 4);
    f16x8 A;
#pragma unroll
    for (int e = 0; e < 4; ++e){ A[e] = (_Float16)v0[e]; A[e+4] = (_Float16)v1[e]; }
#pragma unroll
    for (int c = 0; c < 2; ++c){
      f16x8 B = *(const f16x8*)(FC3T + (size_t)(16*c + li)*256 + kk*32 + lg*8);
      acc[c] = mfma16(A, B, acc[c]);
    }
  }
#pragma unroll
  for (int c = 0; c < 2; ++c){
    int col = 16*c + li;
    float bias = fc3b[col];
#pragma unroll
    for (int j = 0; j < 4; ++j){
      int row = rb + 4*lg + j;
      float am = em[(size_t)(row >> 4)*64 + (row & 15)];
      qo[(size_t)row*32 + col] = (acc[c][j] + bias)*(1.f - am);
    }
  }
}

// --------------------------------------------------------------------- launch
extern "C" void kernel_launch(void* const* d_in, const int* in_sizes, int n_in,
                              void* d_out, int out_size, void* d_ws, size_t ws_size,
                              hipStream_t stream)
{
  // ws layout (bytes) — r3 layout
  constexpr size_t OFF_FC1T   = 0;
  constexpr size_t OFF_MSG1T  = 49152;
  constexpr size_t OFF_AINT   = 98304;
  constexpr size_t OFF_LINT   = 491520;
  constexpr size_t OFF_AOUTT  = 884736;
  constexpr size_t OFF_LOUTT  = 1015808;
  constexpr size_t OFF_GMINT  = 1146880;
  constexpr size_t OFF_GMOUTT = 1540096;
  constexpr size_t OFF_FC2T   = 1671168;
  constexpr size_t OFF_GIHT   = 1933312;
  constexpr size_t OFF_GHHT   = 2326528;
  constexpr size_t OFF_FC3T   = 2719744;
  constexpr size_t OFF_G1T    = 2736128;   // f16 hi+lo pair
  constexpr size_t OFF_GINT   = 2834432;   // pair
  constexpr size_t OFF_WVEFF  = 3620864;   // pair
  constexpr size_t OFF_BEFF   = 3637248;
  constexpr size_t OFF_GATE   = 3637504;   // 131072
  constexpr size_t OFF_X2     = 3768576;   // 33554432
  constexpr size_t OFF_X2M    = 37323008;  // 33554432
  constexpr size_t OFF_GI     = 70877440;  // 100663296
  constexpr size_t NEED       = 171540736;
  if (ws_size < NEED) return;

  char* ws = (char*)d_ws;
  const float* ent = (const float*)d_in[0];
  const float* om  = (const float*)d_in[1];
  const float* em  = (const float*)d_in[2];

  WJobs jb{};
  int nj = 0;
  auto addj = [&](int src_idx, size_t off, int K, int N, int m){
    jb.src[nj] = (const float*)d_in[src_idx]; jb.off[nj] = (unsigned)off;
    jb.K[nj] = K; jb.N[nj] = N; jb.mode[nj] = m; ++nj;
  };
  addj(4,  OFF_FC1T,   96, 256, 0);
  addj(17, OFF_MSG1T,  96, 256, 0);
  addj(6,  OFF_AINT,  256, 768, 0);
  addj(19, OFF_LINT,  256, 768, 0);
  addj(7,  OFF_AOUTT, 256, 256, 0);
  addj(20, OFF_LOUTT, 256, 256, 0);
  addj(22, OFF_GMINT, 256, 768, 0);
  addj(23, OFF_GMOUTT,256, 256, 0);
  addj(9,  OFF_FC2T,  512, 256, 0);
  addj(11, OFF_GIHT,  256, 768, 0);
  addj(12, OFF_GHHT,  256, 768, 0);
  addj(15, OFF_FC3T,  256,  32, 0);
  addj(28, OFF_G1T,    96, 256, 1);
  addj(25, OFF_GINT,  256, 768, 1);
  k0_conv<<<dim3(96, nj), 256, 0, stream>>>(jb, ws);

  // gate-tail precompute: Weff/Wveff/beff
  k0w_gate<<<1, 256, 0, stream>>>(
      (const float*)d_in[26], (const float*)d_in[30],
      (const float*)d_in[27], (const float*)d_in[25],
      (_Float16*)(ws + OFF_WVEFF), (float*)(ws + OFF_BEFF));

  constexpr int SMB = 156672, SMG = 116480, SM3 = 77824;
  (void)hipFuncSetAttribute(reinterpret_cast<const void*>(&k1_branch2),
                            hipFuncAttributeMaxDynamicSharedMemorySize, SMB);
  (void)hipFuncSetAttribute(reinterpret_cast<const void*>(&k1_gate),
                            hipFuncAttributeMaxDynamicSharedMemorySize, SMG);
  (void)hipFuncSetAttribute(reinterpret_cast<const void*>(&k3_gru),
                            hipFuncAttributeMaxDynamicSharedMemorySize, SM3);

  float* qout = (float*)d_out;
  float* hsout = qout + 1048576;
  float* gout = qout + 9437184;

  // merged main+msg branches: 2048 blocks, 2 items each
  k1_branch2<<<2048, 256, SMB, stream>>>(ent, om, em,
      (const _Float16*)(ws + OFF_FC1T),  (const float*)d_in[5],
      (const _Float16*)(ws + OFF_AINT),
      (const _Float16*)(ws + OFF_AOUTT), (const float*)d_in[8],
      (float*)(ws + OFF_X2),
      (const _Float16*)(ws + OFF_MSG1T), (const float*)d_in[18],
      (const _Float16*)(ws + OFF_LINT),
      (const _Float16*)(ws + OFF_LOUTT), (const float*)d_in[21],
      (float*)(ws + OFF_X2M));
  k1_gate<<<2048, 512, SMG, stream>>>(ent, om, em,
      (const _Float16*)(ws + OFF_G1T),   (const float*)d_in[29],
      (const _Float16*)(ws + OFF_GINT),
      (const _Float16*)(ws + OFF_WVEFF),
      (const float*)(ws + OFF_BEFF), (const float*)d_in[31],
      gout, (float*)(ws + OFF_GATE));

  k2_global<<<2048, 256, 0, stream>>>(em,
      (const float*)(ws + OFF_X2), (const float*)(ws + OFF_X2M),
      (const float*)(ws + OFF_GATE),
      (const _Float16*)(ws + OFF_GMINT), (const _Float16*)(ws + OFF_GMOUTT), (const float*)d_in[24],
      (const _Float16*)(ws + OFF_FC2T), (const float*)d_in[10],
      (const _Float16*)(ws + OFF_GIHT), (const float*)d_in[13],
      (float*)(ws + OFF_GI));

  k3_gru<<<32, 256, SM3, stream>>>(
      (const _Float16*)(ws + OFF_GHHT), (const float*)d_in[14],
      (const float*)(ws + OFF_GI), (const float*)d_in[3], hsout);

  k4_q<<<512, 256, 0, stream>>>(
      (const _Float16*)(ws + OFF_FC3T), (const float*)d_in[16],
      em, hsout, qout);
}

// Round 11
// 1584.930 us; speedup vs baseline: 1.3460x; 1.0332x over previous
//
#include <hip/hip_runtime.h>

// EntityAttentionRNNMsgAgent — fused MI355X implementation.
// r11 = r10 + k1_branch2 at 512 threads (8 waves): same 2-item B-sharing,
// tile-space split across 2x waves -> 8 waves/CU (was 4) for latency hiding.
// Stages:
//  K0:  transpose all weights to f16 [N][K] (gate branch: hi/lo split pair)
//  K0w: gate-tail collapse: Weff = Wout@Wg2, Wveff (256x8), beff — f32, 1 block
//  K1b2: merged main+msg branch attention, 2 items/block, 512 thr (2048 blocks)
//  K1g: gate branch, algebraically reduced: split-2 f16 + f32 P.v2 -> og/gate
//  K2:  gated_msg, global attention, fc2, gru-input GEMM (gi); reads gate flag
//  K3:  64-step GRU, row-partitioned (32 blocks x 16 rows), h resident in LDS
//  K4:  q = hs @ fc3 + b, masked

#define DEV __device__ __forceinline__

typedef _Float16 f16x8 __attribute__((ext_vector_type(8)));
typedef float    f32x4 __attribute__((ext_vector_type(4)));

DEV f32x4 mfma16(f16x8 a, f16x8 b, f32x4 c){
  return __builtin_amdgcn_mfma_f32_16x16x32_f16(a, b, c, 0, 0, 0);
}

// A/B fragment pair for optional split-precision (MODE=1: value = hi + lo)
template<int MODE> struct AB {
  f16x8 hi, lo;
  DEV void mf(const AB& b, f32x4& c) const {
    if constexpr (MODE){
      c = mfma16(lo, b.hi, c);
      c = mfma16(hi, b.lo, c);
    }
    c = mfma16(hi, b.hi, c);
  }
};

template<int MODE> DEV AB<MODE> ldW(const _Float16* p, int losz){
  AB<MODE> r; r.hi = *(const f16x8*)p;
  if constexpr (MODE) r.lo = *(const f16x8*)(p + losz);
  return r;
}
template<int MODE> DEV AB<MODE> ldL(const _Float16* ph, const _Float16* pl){
  AB<MODE> r; r.hi = *(const f16x8*)ph;
  if constexpr (MODE) r.lo = *(const f16x8*)pl;
  return r;
}
template<int MODE> DEV AB<MODE> ldF(const float* p){
  AB<MODE> r;
  f32x4 v0 = *(const f32x4*)p, v1 = *(const f32x4*)(p + 4);
#pragma unroll
  for (int i = 0; i < 4; ++i){
    float a = v0[i], b = v1[i];
    _Float16 ah = (_Float16)a, bh = (_Float16)b;
    r.hi[i] = ah; r.hi[i+4] = bh;
    if constexpr (MODE){
      r.lo[i]   = (_Float16)(a - (float)ah);
      r.lo[i+4] = (_Float16)(b - (float)bh);
    }
  }
  return r;
}
template<int MODE> DEV void stL(_Float16* ph, _Float16* pl, int idx, float v){
  _Float16 h = (_Float16)v;
  ph[idx] = h;
  if constexpr (MODE) pl[idx] = (_Float16)(v - (float)h);
}

// ---------------------------------------------------------------- K0: weights
struct WJobs {
  const float* src[15];
  unsigned off[15];
  int K[15], N[15], mode[15];
};

__global__ __launch_bounds__(256) void k0_conv(WJobs jb, char* ws){
  const int job = blockIdx.y;
  const int K = jb.K[job], N = jb.N[job];
  const int total = K * N;
  _Float16* dh = (_Float16*)(ws + jb.off[job]);
  const float* src = jb.src[job];
  const int m = jb.mode[job];
  for (int idx = blockIdx.x*256 + threadIdx.x; idx < total; idx += gridDim.x*256){
    int n = idx / K, k = idx - n*K;
    float v = src[(size_t)k*N + n];
    _Float16 h = (_Float16)v;
    dh[idx] = h;
    if (m) dh[total + idx] = (_Float16)(v - (float)h);
  }
}

// ------------------------------------------------- K0w: gate-tail precompute
__global__ __launch_bounds__(256) void k0w_gate(
    const float* __restrict__ Wout, const float* __restrict__ Wg2,
    const float* __restrict__ bo,   const float* __restrict__ Win,
    _Float16* __restrict__ wveff, float* __restrict__ beff)
{
  __shared__ float weff_s[256*2];
  const int tid = threadIdx.x;
  {
    float a0 = 0.f, a1 = 0.f;
    const float* wr = Wout + (size_t)tid*256;
    for (int f = 0; f < 256; ++f){ float x = wr[f]; a0 += x*Wg2[2*f]; a1 += x*Wg2[2*f+1]; }
    weff_s[tid*2] = a0; weff_s[tid*2+1] = a1;
  }
  if (tid < 2){
    float s = 0.f;
    for (int f = 0; f < 256; ++f) s += bo[f]*Wg2[2*f + tid];
    beff[tid] = s;
  }
  __syncthreads();
  {
    const int j = tid;
    for (int n = 0; n < 16; ++n){
      float v = 0.f;
      if (n < 8){
        int h = n >> 1, c = n & 1;
        const float* wr = Win + (size_t)j*768 + 512 + h*64;
        const float* we = weff_s + (h*64)*2 + c;
        for (int d = 0; d < 64; ++d) v += wr[d]*we[2*d];
      }
      _Float16 hi = (_Float16)v;
      wveff[n*256 + j] = hi;
      wveff[16*256 + n*256 + j] = (_Float16)(v - (float)hi);
    }
  }
}

// ------------------------------------------- K1b2: branch attention, 2 items
// 2048 blocks x 512 threads (8 waves); br = blockIdx.x>>10 selects {main,msg};
// pair p = blockIdx.x&1023 -> items 2p, 2p+1. Weight fragments are loaded once
// per wave and applied to both items; tile-space split across 8 waves.
// wi = w&3 (tile role), ih = w>>2 (half: item or c-subset, phase-dependent).
__global__ __launch_bounds__(512) void k1_branch2(
    const float* __restrict__ ent, const float* __restrict__ om, const float* __restrict__ em,
    const _Float16* __restrict__ W1a, const float* __restrict__ b1a,
    const _Float16* __restrict__ WINa,
    const _Float16* __restrict__ WOUTa, const float* __restrict__ boa,
    float* __restrict__ x2outa,
    const _Float16* __restrict__ W1b, const float* __restrict__ b1b,
    const _Float16* __restrict__ WINb,
    const _Float16* __restrict__ WOUTb, const float* __restrict__ bob,
    float* __restrict__ x2outb)
{
  const int br = blockIdx.x >> 10;
  const int p  = blockIdx.x & 1023;
  const int bb2[2] = { 2*p, 2*p + 1 };
  const _Float16* W1   = br ? W1b   : W1a;
  const float*    b1   = br ? b1b   : b1a;
  const _Float16* WIN  = br ? WINb  : WINa;
  const _Float16* WOUT = br ? WOUTb : WOUTa;
  const float*    bo   = br ? bob   : boa;
  float*          x2out= br ? x2outb: x2outa;

  const int tid = threadIdx.x;
  const int w = tid >> 6, lg = (tid >> 4) & 3, li = tid & 15;
  const int wi = w & 3, ih = w >> 2;

  extern __shared__ char smem[];
  _Float16* x1  = (_Float16*)smem;               // [2][64*264]  67584 B
  _Float16* Ks  = (_Float16*)(smem + 67584);     // [2][64*72]   18432 B
  _Float16* Vs  = (_Float16*)(smem + 86016);     // [2][64*72]T  18432 B
  _Float16* Qs  = (_Float16*)(smem + 104448);    // [2][16*72]    4608 B
  float*    lgs = (float*)(smem + 109056);       // [2][16*72]    9216 B
  _Float16* Ps  = (_Float16*)(smem + 118272);    // [2][16*72]    4608 B
  float*    outp= (float*)(smem + 122880);       // [2][16*264]  33792 B
  // total 156672 B

  // ---- phase 1: x1 = relu(ent @ W1 + b1); wave -> item ih, col-group wi
  {
    const int b = bb2[ih];
    _Float16* x1p = x1 + ih*16896;
    f32x4 acc[4][4];
#pragma unroll
    for (int r = 0; r < 4; ++r)
#pragma unroll
      for (int c = 0; c < 4; ++c) acc[r][c] = 0.f;
#pragma unroll
    for (int kk = 0; kk < 3; ++kk){
      AB<0> a[4];
#pragma unroll
      for (int r = 0; r < 4; ++r)
        a[r] = ldF<0>(ent + ((size_t)b*64 + 16*r + li)*96 + kk*32 + lg*8);
#pragma unroll
      for (int c = 0; c < 4; ++c){
        f16x8 B = *(const f16x8*)(W1 + (size_t)(64*wi + 16*c + li)*96 + kk*32 + lg*8);
#pragma unroll
        for (int r = 0; r < 4; ++r) acc[r][c] = mfma16(a[r].hi, B, acc[r][c]);
      }
    }
#pragma unroll
    for (int c = 0; c < 4; ++c){
      int col = 64*wi + 16*c + li;
      float bias = b1[col];
#pragma unroll
      for (int r = 0; r < 4; ++r)
#pragma unroll
        for (int j = 0; j < 4; ++j){
          float v = fmaxf(acc[r][c][j] + bias, 0.f);
          x1p[(16*r + 4*lg + j)*264 + col] = (_Float16)v;
        }
    }
  }
  __syncthreads();

  // ---- phase 2: per-head attention
  for (int h = 0; h < 4; ++h){
    { // K_h: wave -> keys 16*wi, c-tiles {2ih, 2ih+1}, both items
      f32x4 acc[2][2];
#pragma unroll
      for (int it = 0; it < 2; ++it)
#pragma unroll
        for (int c = 0; c < 2; ++c) acc[it][c] = 0.f;
      for (int kk = 0; kk < 8; ++kk){
        int ao = (16*wi + li)*264 + kk*32 + lg*8;
        f16x8 A0 = *(const f16x8*)(x1 + ao);
        f16x8 A1 = *(const f16x8*)(x1 + 16896 + ao);
#pragma unroll
        for (int cc = 0; cc < 2; ++cc){
          int c = 2*ih + cc;
          f16x8 B = *(const f16x8*)(WIN + (size_t)(256 + 64*h + 16*c + li)*256 + kk*32 + lg*8);
          acc[0][cc] = mfma16(A0, B, acc[0][cc]);
          acc[1][cc] = mfma16(A1, B, acc[1][cc]);
        }
      }
#pragma unroll
      for (int it = 0; it < 2; ++it)
#pragma unroll
        for (int cc = 0; cc < 2; ++cc){
          int c = 2*ih + cc;
#pragma unroll
          for (int j = 0; j < 4; ++j)
            Ks[it*4608 + (16*wi + 4*lg + j)*72 + 16*c + li] = (_Float16)acc[it][cc][j];
        }
    }
    { // V_h (stored transposed): same split
      f32x4 acc[2][2];
#pragma unroll
      for (int it = 0; it < 2; ++it)
#pragma unroll
        for (int c = 0; c < 2; ++c) acc[it][c] = 0.f;
      for (int kk = 0; kk < 8; ++kk){
        int ao = (16*wi + li)*264 + kk*32 + lg*8;
        f16x8 A0 = *(const f16x8*)(x1 + ao);
        f16x8 A1 = *(const f16x8*)(x1 + 16896 + ao);
#pragma unroll
        for (int cc = 0; cc < 2; ++cc){
          int c = 2*ih + cc;
          f16x8 B = *(const f16x8*)(WIN + (size_t)(512 + 64*h + 16*c + li)*256 + kk*32 + lg*8);
          acc[0][cc] = mfma16(A0, B, acc[0][cc]);
          acc[1][cc] = mfma16(A1, B, acc[1][cc]);
        }
      }
#pragma unroll
      for (int it = 0; it < 2; ++it)
#pragma unroll
        for (int cc = 0; cc < 2; ++cc){
          int c = 2*ih + cc;
#pragma unroll
          for (int j = 0; j < 4; ++j)
            Vs[it*4608 + (16*c + li)*72 + 16*wi + 4*lg + j] = (_Float16)acc[it][cc][j];
        }
    }
    { // Q_h: rows 0..15, wave -> dim tile wi, item ih
      f32x4 acc = 0.f;
      for (int kk = 0; kk < 8; ++kk){
        f16x8 A = *(const f16x8*)(x1 + ih*16896 + li*264 + kk*32 + lg*8);
        f16x8 B = *(const f16x8*)(WIN + (size_t)(64*h + 16*wi + li)*256 + kk*32 + lg*8);
        acc = mfma16(A, B, acc);
      }
#pragma unroll
      for (int j = 0; j < 4; ++j)
        Qs[ih*1152 + (4*lg + j)*72 + 16*wi + li] = (_Float16)acc[j];
    }
    __syncthreads();
    { // logits = Q K^T / 8, masked; wave -> keys 16*wi, item ih
      const int b = bb2[ih];
      f32x4 acc = 0.f;
#pragma unroll
      for (int kk = 0; kk < 2; ++kk){
        f16x8 A = *(const f16x8*)(Qs + ih*1152 + li*72 + kk*32 + lg*8);
        f16x8 B = *(const f16x8*)(Ks + ih*4608 + (16*wi + li)*72 + kk*32 + lg*8);
        acc = mfma16(A, B, acc);
      }
#pragma unroll
      for (int j = 0; j < 4; ++j){
        int q = 4*lg + j, key = 16*wi + li;
        float v = acc[j] * 0.125f;
        float m = om[((size_t)b*64 + q)*64 + key];
        if (m > 0.f) v = -1e9f;
        lgs[ih*1152 + q*72 + key] = v;
      }
    }
    __syncthreads();
    { // softmax: 512 threads cover 2 items x 16 q x 16 lanes
      const int it = tid >> 8, q = (tid >> 4) & 15, i16 = tid & 15;
      const int b = bb2[it];
      float pv[4], mx = -3e38f;
#pragma unroll
      for (int u = 0; u < 4; ++u){ pv[u] = lgs[it*1152 + q*72 + i16 + 16*u]; mx = fmaxf(mx, pv[u]); }
#pragma unroll
      for (int d = 1; d < 16; d <<= 1) mx = fmaxf(mx, __shfl_xor(mx, d, 16));
      float s = 0.f;
#pragma unroll
      for (int u = 0; u < 4; ++u){ pv[u] = expf(pv[u] - mx); s += pv[u]; }
#pragma unroll
      for (int d = 1; d < 16; d <<= 1) s += __shfl_xor(s, d, 16);
#pragma unroll
      for (int u = 0; u < 4; ++u){
        int key = i16 + 16*u;
        float m = om[((size_t)b*64 + q)*64 + key];
        Ps[it*1152 + q*72 + key] = (_Float16)((pv[u]/s)*(1.f - m));
      }
    }
    __syncthreads();
    { // out_h = P @ V_h; wave -> dim tile wi, item ih
      f32x4 acc = 0.f;
#pragma unroll
      for (int kk = 0; kk < 2; ++kk){
        f16x8 A = *(const f16x8*)(Ps + ih*1152 + li*72 + kk*32 + lg*8);
        f16x8 B = *(const f16x8*)(Vs + ih*4608 + (16*wi + li)*72 + kk*32 + lg*8);
        acc = mfma16(A, B, acc);
      }
#pragma unroll
      for (int j = 0; j < 4; ++j)
        outp[ih*4224 + (4*lg + j)*264 + 64*h + 16*wi + li] = acc[j];
    }
    __syncthreads();
  }

  // ---- phase 3: out-proj; wave -> col-group wi, c-tiles {2ih,2ih+1}, 2 items
  {
    f32x4 acc[2][2];
#pragma unroll
    for (int it = 0; it < 2; ++it)
#pragma unroll
      for (int c = 0; c < 2; ++c) acc[it][c] = 0.f;
    for (int kk = 0; kk < 8; ++kk){
      AB<0> a0 = ldF<0>(outp + li*264 + kk*32 + lg*8);
      AB<0> a1 = ldF<0>(outp + 4224 + li*264 + kk*32 + lg*8);
#pragma unroll
      for (int cc = 0; cc < 2; ++cc){
        int c = 2*ih + cc;
        f16x8 B = *(const f16x8*)(WOUT + (size_t)(64*wi + 16*c + li)*256 + kk*32 + lg*8);
        acc[0][cc] = mfma16(a0.hi, B, acc[0][cc]);
        acc[1][cc] = mfma16(a1.hi, B, acc[1][cc]);
      }
    }
#pragma unroll
    for (int it = 0; it < 2; ++it){
      const int b = bb2[it];
#pragma unroll
      for (int cc = 0; cc < 2; ++cc){
        int col = 64*wi + 16*(2*ih + cc) + li;
        float bias = bo[col];
#pragma unroll
        for (int j = 0; j < 4; ++j){
          int q = 4*lg + j;
          float v = (acc[it][cc][j] + bias) * (1.f - em[(size_t)b*64 + q]);
          x2out[((size_t)b*16 + q)*256 + col] = v;
        }
      }
    }
  }
}

// --------------------------------------------- K1g: reduced gate branch
// 512 threads = 8 waves, one block per batch item.
__global__ __launch_bounds__(512) void k1_gate(
    const float* __restrict__ ent, const float* __restrict__ om, const float* __restrict__ em,
    const _Float16* __restrict__ W1, const float* __restrict__ b1,
    const _Float16* __restrict__ WIN,
    const _Float16* __restrict__ WVEFF,
    const float* __restrict__ beff, const float* __restrict__ gb2,
    float* __restrict__ og, float* __restrict__ gate)
{
  constexpr int W1SZ = 96*256, WINSZ = 256*768, WVSZ = 16*256;
  const int b = blockIdx.x;
  const int tid = threadIdx.x;
  const int w = tid >> 6, lg = (tid >> 4) & 3, li = tid & 15;

  extern __shared__ char smem[];
  char* sp = smem;
  _Float16* x1h = (_Float16*)sp; sp += 64*264*2;
  _Float16* x1l = (_Float16*)sp; sp += 64*264*2;
  _Float16* Kh  = (_Float16*)sp; sp += 64*72*2;
  _Float16* Kl  = (_Float16*)sp; sp += 64*72*2;
  _Float16* Qh  = (_Float16*)sp; sp += 16*264*2;
  _Float16* Ql  = (_Float16*)sp; sp += 16*264*2;
  float*    lgs = (float*)sp;    sp += 16*72*4;
  float*    Ps  = (float*)sp;    sp += 16*66*4;
  float*    v2s = (float*)sp;    sp += 64*18*4;
  float*  ogacc = (float*)sp;    sp += 32*4;

  // ---- phase 1: x1 = relu(ent @ W1 + b1); wave w -> m-tile w>>1, 8 n-tiles
  {
    const int mt = w >> 1;
    f32x4 acc[8];
#pragma unroll
    for (int c = 0; c < 8; ++c) acc[c] = 0.f;
#pragma unroll
    for (int kk = 0; kk < 3; ++kk){
      AB<1> a = ldF<1>(ent + ((size_t)b*64 + mt*16 + li)*96 + kk*32 + lg*8);
#pragma unroll
      for (int c = 0; c < 8; ++c){
        int nt = (w & 1)*8 + c;
        AB<1> bb = ldW<1>(W1 + (size_t)(nt*16 + li)*96 + kk*32 + lg*8, W1SZ);
        a.mf(bb, acc[c]);
      }
    }
#pragma unroll
    for (int c = 0; c < 8; ++c){
      int col = ((w & 1)*8 + c)*16 + li;
      float bias = b1[col];
#pragma unroll
      for (int j = 0; j < 4; ++j){
        float v = fmaxf(acc[c][j] + bias, 0.f);
        stL<1>(x1h, x1l, (mt*16 + 4*lg + j)*264 + col, v);
      }
    }
  }
  if (tid < 32) ogacc[tid] = 0.f;
  __syncthreads();

  // ---- phase 2: Qfull = x1[0:16] @ Wq (16 n-tiles), v2 = x1 @ Wveff (4 m-tiles)
  {
#pragma unroll
    for (int s = 0; s < 2; ++s){
      int nt = w + s*8;
      f32x4 acc = 0.f;
      for (int kk = 0; kk < 8; ++kk){
        int ao = li*264 + kk*32 + lg*8;
        AB<1> a = ldL<1>(x1h + ao, x1l + ao);
        AB<1> bb = ldW<1>(WIN + (size_t)(nt*16 + li)*256 + kk*32 + lg*8, WINSZ);
        a.mf(bb, acc);
      }
#pragma unroll
      for (int j = 0; j < 4; ++j)
        stL<1>(Qh, Ql, (4*lg + j)*264 + nt*16 + li, acc[j]);
    }
    if (w < 4){   // v2 m-tile w
      f32x4 acc = 0.f;
      for (int kk = 0; kk < 8; ++kk){
        int ao = (w*16 + li)*264 + kk*32 + lg*8;
        AB<1> a = ldL<1>(x1h + ao, x1l + ao);
        AB<1> bb = ldW<1>(WVEFF + (size_t)li*256 + kk*32 + lg*8, WVSZ);
        a.mf(bb, acc);
      }
#pragma unroll
      for (int j = 0; j < 4; ++j)
        v2s[(w*16 + 4*lg + j)*18 + li] = acc[j];
    }
  }
  __syncthreads();

  // ---- head loop
  for (int h = 0; h < 4; ++h){
    { // K_h: wave w -> m-tile w>>1, 2 n-tiles
      const int mt = w >> 1;
      f32x4 acc[2];
      acc[0] = 0.f; acc[1] = 0.f;
      for (int kk = 0; kk < 8; ++kk){
        int ao = (mt*16 + li)*264 + kk*32 + lg*8;
        AB<1> a = ldL<1>(x1h + ao, x1l + ao);
#pragma unroll
        for (int c = 0; c < 2; ++c){
          int nt = (w & 1)*2 + c;
          AB<1> bb = ldW<1>(WIN + (size_t)(256 + h*64 + nt*16 + li)*256 + kk*32 + lg*8, WINSZ);
          a.mf(bb, acc[c]);
        }
      }
#pragma unroll
      for (int c = 0; c < 2; ++c){
        int colb = ((w & 1)*2 + c)*16 + li;
#pragma unroll
        for (int j = 0; j < 4; ++j)
          stL<1>(Kh, Kl, (mt*16 + 4*lg + j)*72 + colb, acc[c][j]);
      }
    }
    __syncthreads();
    if (w < 4){ // logits: keys 16w..16w+15
      f32x4 acc = 0.f;
#pragma unroll
      for (int kk = 0; kk < 2; ++kk){
        int ao = li*264 + h*64 + kk*32 + lg*8;
        AB<1> a = ldL<1>(Qh + ao, Ql + ao);
        int bo_ = (16*w + li)*72 + kk*32 + lg*8;
        AB<1> bb = ldL<1>(Kh + bo_, Kl + bo_);
        a.mf(bb, acc);
      }
#pragma unroll
      for (int j = 0; j < 4; ++j){
        int q = 4*lg + j, key = 16*w + li;
        float v = acc[j] * 0.125f;
        float m = om[((size_t)b*64 + q)*64 + key];
        if (m > 0.f) v = -1e9f;
        lgs[q*72 + key] = v;
      }
    }
    __syncthreads();
    if (tid < 256){ // softmax
      int q = tid >> 4, i16 = tid & 15;
      float pv[4], mx = -3e38f;
#pragma unroll
      for (int u = 0; u < 4; ++u){ pv[u] = lgs[q*72 + i16 + 16*u]; mx = fmaxf(mx, pv[u]); }
#pragma unroll
      for (int d = 1; d < 16; d <<= 1) mx = fmaxf(mx, __shfl_xor(mx, d, 16));
      float s = 0.f;
#pragma unroll
      for (int u = 0; u < 4; ++u){ pv[u] = expf(pv[u] - mx); s += pv[u]; }
#pragma unroll
      for (int d = 1; d < 16; d <<= 1) s += __shfl_xor(s, d, 16);
#pragma unroll
      for (int u = 0; u < 4; ++u){
        int key = i16 + 16*u;
        float m = om[((size_t)b*64 + q)*64 + key];
        Ps[q*66 + key] = (pv[u]/s)*(1.f - m);
      }
    }
    __syncthreads();
    if (tid < 256){ // og += P_h . v2_h  (f32)
      int q = tid >> 4, l16 = tid & 15;
      float a0 = 0.f, a1 = 0.f;
#pragma unroll
      for (int u = 0; u < 4; ++u){
        int k = l16 + 16*u;
        float p = Ps[q*66 + k];
        a0 += p * v2s[k*18 + h*2];
        a1 += p * v2s[k*18 + h*2 + 1];
      }
#pragma unroll
      for (int d = 1; d < 16; d <<= 1){ a0 += __shfl_xor(a0, d, 16); a1 += __shfl_xor(a1, d, 16); }
      if (l16 == 0){ ogacc[q*2] += a0; ogacc[q*2 + 1] += a1; }
    }
    __syncthreads();
  }
  // epilogue: og + gate
  if (tid < 16){
    int q = tid;
    float am = em[(size_t)b*64 + q];
    float g0 = (1.f - am)*(ogacc[2*q]     + beff[0]) + gb2[0];
    float g1 = (1.f - am)*(ogacc[2*q + 1] + beff[1]) + gb2[1];
    og[((size_t)b*16 + q)*2]     = g0;
    og[((size_t)b*16 + q)*2 + 1] = g1;
    gate[(size_t)b*16 + q] = (g1 > g0) ? 1.f : 0.f;
  }
}

// ----------------------------------------- K2: gate, global attention, fc2, gi
__global__ __launch_bounds__(256) void k2_global(
    const float* __restrict__ em,
    const float* __restrict__ x2, const float* __restrict__ x2m,
    const float* __restrict__ gate,
    const _Float16* __restrict__ GMIN, const _Float16* __restrict__ GMOUT, const float* __restrict__ gob,
    const _Float16* __restrict__ FC2T, const float* __restrict__ fc2b,
    const _Float16* __restrict__ GIHT, const float* __restrict__ gib,
    float* __restrict__ gi)
{
  const int b = blockIdx.x;
  const int tid = threadIdx.x;
  const int w = tid >> 6, lg = (tid >> 4) & 3, li = tid & 15;

  __shared__ float gate_s[16];
  __shared__ __align__(16) _Float16 gm_s[16*264];
  __shared__ __align__(16) _Float16 Q2[16*72];
  __shared__ __align__(16) _Float16 K2s[16*72];
  __shared__ __align__(16) _Float16 Vt2[64*40];
  __shared__ float lg2[16*24];
  __shared__ __align__(16) _Float16 P2[16*40];
  __shared__ __align__(16) float outp[16*264];
  __shared__ __align__(16) _Float16 cat_s[16*520];
  __shared__ __align__(16) _Float16 x3_s[16*264];

  if (tid < 16) gate_s[tid] = gate[(size_t)b*16 + tid];
  __syncthreads();
  for (int idx = tid; idx < 4096; idx += 256){
    int q = idx >> 8, d = idx & 255;
    gm_s[q*264 + d]  = (_Float16)(x2m[((size_t)b*16 + q)*256 + d] * gate_s[q]);
    cat_s[q*520 + d] = (_Float16)(x2[((size_t)b*16 + q)*256 + d]);
  }
  for (int idx = tid; idx < 64*40; idx += 256) Vt2[idx] = (_Float16)0.f;
  for (int idx = tid; idx < 16*40; idx += 256) P2[idx] = (_Float16)0.f;
  __syncthreads();
  for (int h = 0; h < 4; ++h){
    {
      f32x4 aq = 0.f, ak = 0.f, av = 0.f;
      for (int kk = 0; kk < 8; ++kk){
        f16x8 A  = *(const f16x8*)(gm_s + li*264 + kk*32 + lg*8);
        f16x8 Bq = *(const f16x8*)(GMIN + (size_t)(      64*h + 16*w + li)*256 + kk*32 + lg*8);
        f16x8 Bk = *(const f16x8*)(GMIN + (size_t)(256 + 64*h + 16*w + li)*256 + kk*32 + lg*8);
        f16x8 Bv = *(const f16x8*)(GMIN + (size_t)(512 + 64*h + 16*w + li)*256 + kk*32 + lg*8);
        aq = mfma16(A, Bq, aq); ak = mfma16(A, Bk, ak); av = mfma16(A, Bv, av);
      }
#pragma unroll
      for (int j = 0; j < 4; ++j){
        int rw = 4*lg + j, dim = 16*w + li;
        Q2[rw*72 + dim]  = (_Float16)aq[j];
        K2s[rw*72 + dim] = (_Float16)ak[j];
        Vt2[dim*40 + rw] = (_Float16)av[j];
      }
    }
    __syncthreads();
    if (w == 0){
      f32x4 acc = 0.f;
#pragma unroll
      for (int kk = 0; kk < 2; ++kk){
        f16x8 A = *(const f16x8*)(Q2  + li*72 + kk*32 + lg*8);
        f16x8 B = *(const f16x8*)(K2s + li*72 + kk*32 + lg*8);
        acc = mfma16(A, B, acc);
      }
      float amk = em[(size_t)b*64 + li];
#pragma unroll
      for (int j = 0; j < 4; ++j){
        int q = 4*lg + j;
        float amq = em[(size_t)b*64 + q];
        float m = 1.f - (1.f - amq)*(1.f - amk);
        float v = acc[j]*0.125f;
        if (m > 0.f) v = -1e9f;
        lg2[q*24 + li] = v;
      }
    }
    __syncthreads();
    {
      int q = tid >> 4, key = tid & 15;
      float v = lg2[q*24 + key];
      float mx = v;
#pragma unroll
      for (int d = 1; d < 16; d <<= 1) mx = fmaxf(mx, __shfl_xor(mx, d, 16));
      float pe = expf(v - mx);
      float s = pe;
#pragma unroll
      for (int d = 1; d < 16; d <<= 1) s += __shfl_xor(s, d, 16);
      float amq = em[(size_t)b*64 + q], amk = em[(size_t)b*64 + key];
      float m = 1.f - (1.f - amq)*(1.f - amk);
      P2[q*40 + key] = (_Float16)((pe/s)*(1.f - m));
    }
    __syncthreads();
    {
      f32x4 acc = 0.f;
      f16x8 A = *(const f16x8*)(P2 + li*40 + lg*8);
      f16x8 B = *(const f16x8*)(Vt2 + (16*w + li)*40 + lg*8);
      acc = mfma16(A, B, acc);
#pragma unroll
      for (int j = 0; j < 4; ++j)
        outp[(4*lg + j)*264 + 64*h + 16*w + li] = acc[j];
    }
    __syncthreads();
  }
  {
    f32x4 acc[4];
#pragma unroll
    for (int c = 0; c < 4; ++c) acc[c] = 0.f;
    for (int kk = 0; kk < 8; ++kk){
      const float* ap = outp + li*264 + kk*32 + lg*8;
      f32x4 v0 = *(const f32x4*)ap, v1 = *(const f32x4*)(ap + 4);
      f16x8 A;
#pragma unroll
      for (int e = 0; e < 4; ++e){ A[e] = (_Float16)v0[e]; A[e+4] = (_Float16)v1[e]; }
#pragma unroll
      for (int c = 0; c < 4; ++c){
        f16x8 B = *(const f16x8*)(GMOUT + (size_t)(64*w + 16*c + li)*256 + kk*32 + lg*8);
        acc[c] = mfma16(A, B, acc[c]);
      }
    }
#pragma unroll
    for (int c = 0; c < 4; ++c){
      int col = 64*w + 16*c + li;
      float bias = gob[col];
#pragma unroll
      for (int j = 0; j < 4; ++j){
        int q = 4*lg + j;
        float v = (acc[c][j] + bias)*(1.f - em[(size_t)b*64 + q]);
        cat_s[q*520 + 256 + col] = (_Float16)v;
      }
    }
  }
  __syncthreads();
  {
    f32x4 acc[4];
#pragma unroll
    for (int c = 0; c < 4; ++c) acc[c] = 0.f;
    for (int kk = 0; kk < 16; ++kk){
      f16x8 A = *(const f16x8*)(cat_s + li*520 + kk*32 + lg*8);
#pragma unroll
      for (int c = 0; c < 4; ++c){
        f16x8 B = *(const f16x8*)(FC2T + (size_t)(64*w + 16*c + li)*512 + kk*32 + lg*8);
        acc[c] = mfma16(A, B, acc[c]);
      }
    }
#pragma unroll
    for (int c = 0; c < 4; ++c){
      int col = 64*w + 16*c + li;
      float bias = fc2b[col];
#pragma unroll
      for (int j = 0; j < 4; ++j)
        x3_s[(4*lg + j)*264 + col] = (_Float16)fmaxf(acc[c][j] + bias, 0.f);
    }
  }
  __syncthreads();
  {
    const int r0 = (b >> 6)*16, t = b & 63;
    f32x4 acc[12];
#pragma unroll
    for (int cc = 0; cc < 12; ++cc) acc[cc] = 0.f;
    for (int kk = 0; kk < 8; ++kk){
      f16x8 A = *(const f16x8*)(x3_s + li*264 + kk*32 + lg*8);
#pragma unroll
      for (int cc = 0; cc < 12; ++cc){
        int col = (w*12 + cc)*16 + li;
        f16x8 B = *(const f16x8*)(GIHT + (size_t)col*256 + kk*32 + lg*8);
        acc[cc] = mfma16(A, B, acc[cc]);
      }
    }
#pragma unroll
    for (int cc = 0; cc < 12; ++cc){
      int col = (w*12 + cc)*16 + li;
      float bias = gib[col];
#pragma unroll
      for (int j = 0; j < 4; ++j){
        int q = 4*lg + j;
        gi[((size_t)((r0 + q)*64 + t))*768 + col] = acc[cc][j] + bias;
      }
    }
  }
}

// ------------------------------------------------------------------ K3: GRU
__global__ __launch_bounds__(256) void k3_gru(
    const _Float16* __restrict__ WHH, const float* __restrict__ bhh,
    const float* __restrict__ gi, const float* __restrict__ h0,
    float* __restrict__ hs)
{
  const int rb = blockIdx.x;
  const int row0 = rb * 16;
  const int tid = threadIdx.x;
  const int w = tid >> 6, lg = (tid >> 4) & 3, li = tid & 15;

  extern __shared__ char smem3[];
  _Float16* hf16 = (_Float16*)smem3;
  float* hf32 = (float*)(smem3 + 8448);
  float* gh   = (float*)(smem3 + 8448 + 16640);
  float* bhs  = (float*)(smem3 + 8448 + 16640 + 49664);

  for (int idx = tid; idx < 768; idx += 256) bhs[idx] = bhh[idx];
  for (int idx = tid; idx < 4096; idx += 256){
    int r = idx >> 8, d = idx & 255;
    float v = h0[(size_t)(row0 + r)*256 + d];
    hf32[r*260 + d] = v;
    hf16[r*264 + d] = (_Float16)v;
  }
  __syncthreads();

  const int er = tid >> 4;
  const int d0 = (tid & 15) * 16;

  for (int t = 0; t < 64; ++t){
    const float* gp = gi + ((size_t)(row0 + er)*64 + t)*768 + d0;
    f32x4 gr[4], gz[4], gn[4];
#pragma unroll
    for (int v = 0; v < 4; ++v){
      gr[v] = *(const f32x4*)(gp + v*4);
      gz[v] = *(const f32x4*)(gp + 256 + v*4);
      gn[v] = *(const f32x4*)(gp + 512 + v*4);
    }
    f16x8 a[8];
#pragma unroll
    for (int kk = 0; kk < 8; ++kk)
      a[kk] = *(const f16x8*)(hf16 + li*264 + kk*32 + lg*8);
    f32x4 acc[12];
#pragma unroll
    for (int c = 0; c < 12; ++c) acc[c] = 0.f;
#pragma unroll
    for (int c = 0; c < 12; ++c){
      const _Float16* bp = WHH + (size_t)(w*192 + c*16 + li)*256 + lg*8;
#pragma unroll
      for (int kk = 0; kk < 8; ++kk)
        acc[c] = mfma16(a[kk], *(const f16x8*)(bp + kk*32), acc[c]);
    }
#pragma unroll
    for (int c = 0; c < 12; ++c){
      int col = w*192 + c*16 + li;
#pragma unroll
      for (int j = 0; j < 4; ++j)
        gh[(4*lg + j)*776 + col] = acc[c][j];
    }
    __syncthreads();
    {
      float* hp32 = hf32 + er*260 + d0;
      float* hsp  = hs + ((size_t)(rb*64 + t)*16 + er)*256 + d0;
      f16x8 hv8[2];
#pragma unroll
      for (int v = 0; v < 4; ++v){
        f32x4 xr = *(const f32x4*)(gh + er*776 +       d0 + v*4);
        f32x4 xz = *(const f32x4*)(gh + er*776 + 256 + d0 + v*4);
        f32x4 xn = *(const f32x4*)(gh + er*776 + 512 + d0 + v*4);
        f32x4 hold = *(const f32x4*)(hp32 + v*4);
        f32x4 hout;
#pragma unroll
        for (int e = 0; e < 4; ++e){
          int d = d0 + v*4 + e;
          float rr_ = 1.f/(1.f + expf(-(gr[v][e] + xr[e] + bhs[d])));
          float zz  = 1.f/(1.f + expf(-(gz[v][e] + xz[e] + bhs[256 + d])));
          float nn  = tanhf(gn[v][e] + rr_*(xn[e] + bhs[512 + d]));
          float hv = (1.f - zz)*nn + zz*hold[e];
          hout[e] = hv;
          int sl = v*4 + e;
          hv8[sl >> 3][sl & 7] = (_Float16)hv;
        }
        *(f32x4*)(hp32 + v*4) = hout;
        *(f32x4*)(hsp + v*4)  = hout;
      }
      *(f16x8*)(hf16 + er*264 + d0)     = hv8[0];
      *(f16x8*)(hf16 + er*264 + d0 + 8) = hv8[1];
    }
    __syncthreads();
  }
}

// ------------------------------------------------------------------ K4: q out
__global__ __launch_bounds__(256) void k4_q(
    const _Float16* __restrict__ FC3T, const float* __restrict__ fc3b,
    const float* __restrict__ em, const float* __restrict__ hs, float* __restrict__ qo)
{
  const int tid = threadIdx.x;
  const int w = tid >> 6, lg = (tid >> 4) & 3, li = tid & 15;
  const int rb = blockIdx.x*64 + 16*w;
  f32x4 acc[2];
#pragma unroll
  for (int c = 0; c < 2; ++c) acc[c] = 0.f;
  for (int kk = 0; kk < 8; ++kk){
    const float* ap = hs + (size_t)(rb + li)*256 + kk*32 + lg*8;
    f32x4 v0 = *(const f32x4*)ap, v1 = *(const f32x4*)(ap + 4);
    f16x8 A;
#pragma unroll
    for (int e = 0; e < 4; ++e){ A[e] = (_Float16)v0[e]; A[e+4] = (_Float16)v1[e]; }
#pragma unroll
    for (int c = 0; c < 2; ++c){
      f16x8 B = *(const f16x8*)(FC3T + (size_t)(16*c + li)*256 + kk*32 + lg*8);
      acc[c] = mfma16(A, B, acc[c]);
    }
  }
#pragma unroll
  for (int c = 0; c < 2; ++c){
    int col = 16*c + li;
    float bias = fc3b[col];
#pragma unroll
    for (int j = 0; j < 4; ++j){
      int row = rb + 4*lg + j;
      float am = em[(size_t)(row >> 4)*64 + (row & 15)];
      qo[(size_t)row*32 + col] = (acc[c][j] + bias)*(1.f - am);
    }
  }
}

// --------------------------------------------------------------------- launch
extern "C" void kernel_launch(void* const* d_in, const int* in_sizes, int n_in,
                              void* d_out, int out_size, void* d_ws, size_t ws_size,
                              hipStream_t stream)
{
  // ws layout (bytes) — r3 layout
  constexpr size_t OFF_FC1T   = 0;
  constexpr size_t OFF_MSG1T  = 49152;
  constexpr size_t OFF_AINT   = 98304;
  constexpr size_t OFF_LINT   = 491520;
  constexpr size_t OFF_AOUTT  = 884736;
  constexpr size_t OFF_LOUTT  = 1015808;
  constexpr size_t OFF_GMINT  = 1146880;
  constexpr size_t OFF_GMOUTT = 1540096;
  constexpr size_t OFF_FC2T   = 1671168;
  constexpr size_t OFF_GIHT   = 1933312;
  constexpr size_t OFF_GHHT   = 2326528;
  constexpr size_t OFF_FC3T   = 2719744;
  constexpr size_t OFF_G1T    = 2736128;   // f16 hi+lo pair
  constexpr size_t OFF_GINT   = 2834432;   // pair
  constexpr size_t OFF_WVEFF  = 3620864;   // pair
  constexpr size_t OFF_BEFF   = 3637248;
  constexpr size_t OFF_GATE   = 3637504;   // 131072
  constexpr size_t OFF_X2     = 3768576;   // 33554432
  constexpr size_t OFF_X2M    = 37323008;  // 33554432
  constexpr size_t OFF_GI     = 70877440;  // 100663296
  constexpr size_t NEED       = 171540736;
  if (ws_size < NEED) return;

  char* ws = (char*)d_ws;
  const float* ent = (const float*)d_in[0];
  const float* om  = (const float*)d_in[1];
  const float* em  = (const float*)d_in[2];

  WJobs jb{};
  int nj = 0;
  auto addj = [&](int src_idx, size_t off, int K, int N, int m){
    jb.src[nj] = (const float*)d_in[src_idx]; jb.off[nj] = (unsigned)off;
    jb.K[nj] = K; jb.N[nj] = N; jb.mode[nj] = m; ++nj;
  };
  addj(4,  OFF_FC1T,   96, 256, 0);
  addj(17, OFF_MSG1T,  96, 256, 0);
  addj(6,  OFF_AINT,  256, 768, 0);
  addj(19, OFF_LINT,  256, 768, 0);
  addj(7,  OFF_AOUTT, 256, 256, 0);
  addj(20, OFF_LOUTT, 256, 256, 0);
  addj(22, OFF_GMINT, 256, 768, 0);
  addj(23, OFF_GMOUTT,256, 256, 0);
  addj(9,  OFF_FC2T,  512, 256, 0);
  addj(11, OFF_GIHT,  256, 768, 0);
  addj(12, OFF_GHHT,  256, 768, 0);
  addj(15, OFF_FC3T,  256,  32, 0);
  addj(28, OFF_G1T,    96, 256, 1);
  addj(25, OFF_GINT,  256, 768, 1);
  k0_conv<<<dim3(96, nj), 256, 0, stream>>>(jb, ws);

  // gate-tail precompute: Weff/Wveff/beff
  k0w_gate<<<1, 256, 0, stream>>>(
      (const float*)d_in[26], (const float*)d_in[30],
      (const float*)d_in[27], (const float*)d_in[25],
      (_Float16*)(ws + OFF_WVEFF), (float*)(ws + OFF_BEFF));

  constexpr int SMB = 156672, SMG = 116480, SM3 = 77824;
  (void)hipFuncSetAttribute(reinterpret_cast<const void*>(&k1_branch2),
                            hipFuncAttributeMaxDynamicSharedMemorySize, SMB);
  (void)hipFuncSetAttribute(reinterpret_cast<const void*>(&k1_gate),
                            hipFuncAttributeMaxDynamicSharedMemorySize, SMG);
  (void)hipFuncSetAttribute(reinterpret_cast<const void*>(&k3_gru),
                            hipFuncAttributeMaxDynamicSharedMemorySize, SM3);

  float* qout = (float*)d_out;
  float* hsout = qout + 1048576;
  float* gout = qout + 9437184;

  // merged main+msg branches: 2048 blocks, 2 items each, 512 threads
  k1_branch2<<<2048, 512, SMB, stream>>>(ent, om, em,
      (const _Float16*)(ws + OFF_FC1T),  (const float*)d_in[5],
      (const _Float16*)(ws + OFF_AINT),
      (const _Float16*)(ws + OFF_AOUTT), (const float*)d_in[8],
      (float*)(ws + OFF_X2),
      (const _Float16*)(ws + OFF_MSG1T), (const float*)d_in[18],
      (const _Float16*)(ws + OFF_LINT),
      (const _Float16*)(ws + OFF_LOUTT), (const float*)d_in[21],
      (float*)(ws + OFF_X2M));
  k1_gate<<<2048, 512, SMG, stream>>>(ent, om, em,
      (const _Float16*)(ws + OFF_G1T),   (const float*)d_in[29],
      (const _Float16*)(ws + OFF_GINT),
      (const _Float16*)(ws + OFF_WVEFF),
      (const float*)(ws + OFF_BEFF), (const float*)d_in[31],
      gout, (float*)(ws + OFF_GATE));

  k2_global<<<2048, 256, 0, stream>>>(em,
      (const float*)(ws + OFF_X2), (const float*)(ws + OFF_X2M),
      (const float*)(ws + OFF_GATE),
      (const _Float16*)(ws + OFF_GMINT), (const _Float16*)(ws + OFF_GMOUTT), (const float*)d_in[24],
      (const _Float16*)(ws + OFF_FC2T), (const float*)d_in[10],
      (const _Float16*)(ws + OFF_GIHT), (const float*)d_in[13],
      (float*)(ws + OFF_GI));

  k3_gru<<<32, 256, SM3, stream>>>(
      (const _Float16*)(ws + OFF_GHHT), (const float*)d_in[14],
      (const float*)(ws + OFF_GI), (const float*)d_in[3], hsout);

  k4_q<<<512, 256, 0, stream>>>(
      (const _Float16*)(ws + OFF_FC3T), (const float*)d_in[16],
      em, hsout, qout);
}